// Round 1
// baseline (909.660 us; speedup 1.0000x reference)
//
#include <hip/hip_runtime.h>
#include <math.h>

#define C_DIM 512
#define N_DIM 2048
#define B_DIM 4
#define NGRP 32
#define GCH 16          // channels per group
#define NHEAD 8
#define HDIM 64
#define EPSV 1e-6f

// ---------------------------------------------------------------------------
// GroupNorm: one block per (b, group). Group slab = GCH*N_DIM = 32768 floats,
// contiguous in memory.
// ---------------------------------------------------------------------------
__global__ __launch_bounds__(256) void gn_kernel(const float* __restrict__ x,
                                                 const float* __restrict__ gamma,
                                                 const float* __restrict__ beta,
                                                 float* __restrict__ h) {
    const int GSZ = GCH * N_DIM;            // 32768
    int bg = blockIdx.x;
    int b = bg / NGRP, g = bg % NGRP;
    size_t base = ((size_t)b * C_DIM + (size_t)g * GCH) * N_DIM;
    const float4* x4 = (const float4*)(x + base);
    float4* h4 = (float4*)(h + base);
    int tid = threadIdx.x;

    float s = 0.f, ss = 0.f;
    #pragma unroll
    for (int it = 0; it < GSZ / 4 / 256; ++it) {
        float4 v = x4[tid + it * 256];
        s  += v.x + v.y + v.z + v.w;
        ss += v.x * v.x + v.y * v.y + v.z * v.z + v.w * v.w;
    }
    __shared__ float rs[256], rss[256];
    rs[tid] = s; rss[tid] = ss;
    __syncthreads();
    for (int off = 128; off > 0; off >>= 1) {
        if (tid < off) { rs[tid] += rs[tid + off]; rss[tid] += rss[tid + off]; }
        __syncthreads();
    }
    float mean = rs[0] * (1.f / GSZ);
    float var  = rss[0] * (1.f / GSZ) - mean * mean;
    float rstd = rsqrtf(var + EPSV);

    #pragma unroll
    for (int it = 0; it < GSZ / 4 / 256; ++it) {
        int i4 = tid + it * 256;
        float4 v = x4[i4];
        int c = g * GCH + (i4 >> 9);        // i4*4 / 2048
        float ga = gamma[c] * rstd;
        float be = beta[c] - mean * ga;
        v.x = v.x * ga + be;
        v.y = v.y * ga + be;
        v.z = v.z * ga + be;
        v.w = v.w * ga + be;
        h4[i4] = v;
    }
}

// ---------------------------------------------------------------------------
// Pointwise conv as GEMM: out[b][o][n] = sum_c W[o][c]*in[b][c][n] + bias[o]
// (+ residual). Tile 64(o) x 64(n) x 16(k); 256 threads; 4x4 per thread.
// ---------------------------------------------------------------------------
template <bool RES>
__global__ __launch_bounds__(256) void conv_kernel(const float* __restrict__ W,
                                                   const float* __restrict__ bias,
                                                   const float* __restrict__ in,
                                                   const float* __restrict__ res,
                                                   float* __restrict__ out) {
    __shared__ float Ws[16][64];   // [k][o]  (transposed W tile)
    __shared__ float Hs[16][64];   // [k][n]
    int bn = blockIdx.x * 64;
    int bo = blockIdx.y * 64;
    int b  = blockIdx.z;
    const float* inb = in + (size_t)b * C_DIM * N_DIM;
    int tid = threadIdx.x;
    int tx = tid & 15, ty = tid >> 4;

    float acc[4][4] = {};
    for (int k0 = 0; k0 < C_DIM; k0 += 16) {
        // W tile: 64 rows(o) x 16 cols(k), store transposed into Ws[k][o]
        {
            int r = tid >> 2, c4 = (tid & 3) << 2;
            float4 w4 = *(const float4*)&W[(size_t)(bo + r) * C_DIM + k0 + c4];
            Ws[c4 + 0][r] = w4.x;
            Ws[c4 + 1][r] = w4.y;
            Ws[c4 + 2][r] = w4.z;
            Ws[c4 + 3][r] = w4.w;
        }
        // H tile: 16 rows(k) x 64 cols(n), direct float4
        {
            int rr = tid >> 4, cc4 = (tid & 15) << 2;
            *(float4*)&Hs[rr][cc4] =
                *(const float4*)&inb[(size_t)(k0 + rr) * N_DIM + bn + cc4];
        }
        __syncthreads();
        #pragma unroll
        for (int kk = 0; kk < 16; ++kk) {
            float4 a4 = *(const float4*)&Ws[kk][ty * 4];
            float4 b4 = *(const float4*)&Hs[kk][tx * 4];
            float a[4] = {a4.x, a4.y, a4.z, a4.w};
            float bv[4] = {b4.x, b4.y, b4.z, b4.w};
            #pragma unroll
            for (int i = 0; i < 4; ++i)
                #pragma unroll
                for (int j = 0; j < 4; ++j)
                    acc[i][j] = fmaf(a[i], bv[j], acc[i][j]);
        }
        __syncthreads();
    }
    #pragma unroll
    for (int i = 0; i < 4; ++i) {
        int o = bo + ty * 4 + i;
        float bi = bias[o];
        size_t off = ((size_t)b * C_DIM + o) * N_DIM + bn + tx * 4;
        float4 r4 = make_float4(0.f, 0.f, 0.f, 0.f);
        if (RES) r4 = *(const float4*)&res[off];
        float4 o4;
        o4.x = acc[i][0] + bi + r4.x;
        o4.y = acc[i][1] + bi + r4.y;
        o4.z = acc[i][2] + bi + r4.z;
        o4.w = acc[i][3] + bi + r4.w;
        *(float4*)&out[off] = o4;
    }
}

// ---------------------------------------------------------------------------
// Flash attention, fp32. One block per (b*NHEAD + h, 64-query tile).
// Q/K/V tiles [c][pos] in LDS; S/P in Ss[64][65]; O in registers [c][q] 4x4.
// ---------------------------------------------------------------------------
__global__ __launch_bounds__(256) void attn_kernel(const float* __restrict__ q,
                                                   const float* __restrict__ k,
                                                   const float* __restrict__ v,
                                                   float* __restrict__ o) {
    __shared__ float Qs[HDIM][64];   // [c][q]
    __shared__ float Ks[HDIM][64];   // [c][k]
    __shared__ float Vs[HDIM][64];   // [c][k]
    __shared__ float Ss[64][65];     // [q][k] padded
    __shared__ float m_s[64], l_s[64], f_s[64];

    int q0 = blockIdx.x * 64;
    int bh = blockIdx.y;
    int b = bh >> 3, hh = bh & 7;
    size_t base = ((size_t)b * C_DIM + (size_t)hh * HDIM) * N_DIM;
    int tid = threadIdx.x;
    int tx = tid & 15, ty = tid >> 4;

    #pragma unroll
    for (int it = 0; it < 4; ++it) {
        int idx = tid + it * 256;          // float4 index in 64x64 tile
        int c = idx >> 4, q4 = (idx & 15) << 2;
        *(float4*)&Qs[c][q4] = *(const float4*)&q[base + (size_t)c * N_DIM + q0 + q4];
    }
    if (tid < 64) { m_s[tid] = -INFINITY; l_s[tid] = 0.f; }
    float O[4][4] = {};
    __syncthreads();

    const float scale = 0.044194173824159216f;   // 512^-0.5

    for (int kt = 0; kt < N_DIM / 64; ++kt) {
        int k0 = kt * 64;
        #pragma unroll
        for (int it = 0; it < 4; ++it) {
            int idx = tid + it * 256;
            int c = idx >> 4, k4 = (idx & 15) << 2;
            *(float4*)&Ks[c][k4] = *(const float4*)&k[base + (size_t)c * N_DIM + k0 + k4];
            *(float4*)&Vs[c][k4] = *(const float4*)&v[base + (size_t)c * N_DIM + k0 + k4];
        }
        __syncthreads();

        // S = scale * Q^T K  (qi = ty*4+i, kj = tx*4+j)
        float acc[4][4] = {};
        #pragma unroll
        for (int c = 0; c < HDIM; ++c) {
            float4 a4 = *(const float4*)&Qs[c][ty * 4];
            float4 b4 = *(const float4*)&Ks[c][tx * 4];
            float a[4] = {a4.x, a4.y, a4.z, a4.w};
            float bv[4] = {b4.x, b4.y, b4.z, b4.w};
            #pragma unroll
            for (int i = 0; i < 4; ++i)
                #pragma unroll
                for (int j = 0; j < 4; ++j)
                    acc[i][j] = fmaf(a[i], bv[j], acc[i][j]);
        }
        #pragma unroll
        for (int i = 0; i < 4; ++i)
            #pragma unroll
            for (int j = 0; j < 4; ++j)
                Ss[ty * 4 + i][tx * 4 + j] = acc[i][j] * scale;
        __syncthreads();

        // online softmax row phase: 4 lanes per row
        {
            int r = tid >> 2, qu = tid & 3;
            float mt = -INFINITY;
            #pragma unroll
            for (int c2 = 0; c2 < 16; ++c2) mt = fmaxf(mt, Ss[r][qu * 16 + c2]);
            mt = fmaxf(mt, __shfl_xor(mt, 1, 64));
            mt = fmaxf(mt, __shfl_xor(mt, 2, 64));
            float mp = m_s[r];
            float mn = fmaxf(mp, mt);
            float fac = __expf(mp - mn);     // 0 when mp == -inf
            float psum = 0.f;
            #pragma unroll
            for (int c2 = 0; c2 < 16; ++c2) {
                float p = __expf(Ss[r][qu * 16 + c2] - mn);
                Ss[r][qu * 16 + c2] = p;
                psum += p;
            }
            psum += __shfl_xor(psum, 1, 64);
            psum += __shfl_xor(psum, 2, 64);
            if (qu == 0) { l_s[r] = l_s[r] * fac + psum; m_s[r] = mn; f_s[r] = fac; }
        }
        __syncthreads();

        // O[cc][q] = O*fac[q] + sum_k Vs[cc][k] * P[q][k]
        float fj[4];
        #pragma unroll
        for (int j = 0; j < 4; ++j) fj[j] = f_s[tx * 4 + j];
        #pragma unroll
        for (int i = 0; i < 4; ++i)
            #pragma unroll
            for (int j = 0; j < 4; ++j)
                O[i][j] *= fj[j];
        #pragma unroll
        for (int kk = 0; kk < 64; ++kk) {
            float a[4], bq[4];
            #pragma unroll
            for (int i = 0; i < 4; ++i) a[i] = Vs[ty * 4 + i][kk];
            #pragma unroll
            for (int j = 0; j < 4; ++j) bq[j] = Ss[tx * 4 + j][kk];
            #pragma unroll
            for (int i = 0; i < 4; ++i)
                #pragma unroll
                for (int j = 0; j < 4; ++j)
                    O[i][j] = fmaf(a[i], bq[j], O[i][j]);
        }
        __syncthreads();   // protect Ks/Vs/Ss before next tile's loads
    }

    float linv[4];
    #pragma unroll
    for (int j = 0; j < 4; ++j) linv[j] = 1.f / l_s[tx * 4 + j];
    #pragma unroll
    for (int i = 0; i < 4; ++i) {
        float4 o4;
        o4.x = O[i][0] * linv[0];
        o4.y = O[i][1] * linv[1];
        o4.z = O[i][2] * linv[2];
        o4.w = O[i][3] * linv[3];
        *(float4*)&o[base + (size_t)(ty * 4 + i) * N_DIM + q0 + tx * 4] = o4;
    }
}

// ---------------------------------------------------------------------------
extern "C" void kernel_launch(void* const* d_in, const int* in_sizes, int n_in,
                              void* d_out, int out_size, void* d_ws, size_t ws_size,
                              hipStream_t stream) {
    (void)in_sizes; (void)n_in; (void)out_size; (void)ws_size;
    const float* x     = (const float*)d_in[0];
    const float* gam   = (const float*)d_in[1];
    const float* bet   = (const float*)d_in[2];
    const float* q_w   = (const float*)d_in[3];
    const float* q_b   = (const float*)d_in[4];
    const float* k_w   = (const float*)d_in[5];
    const float* k_b   = (const float*)d_in[6];
    const float* v_w   = (const float*)d_in[7];
    const float* v_b   = (const float*)d_in[8];
    const float* p_w   = (const float*)d_in[9];
    const float* p_b   = (const float*)d_in[10];
    float* out = (float*)d_out;

    const size_t SZ = (size_t)B_DIM * C_DIM * N_DIM;   // 4,194,304
    float* ws = (float*)d_ws;
    float* h  = ws;
    float* qb = ws + SZ;
    float* kb = ws + 2 * SZ;
    float* vb = ws + 3 * SZ;
    float* at = ws + 4 * SZ;

    gn_kernel<<<B_DIM * NGRP, 256, 0, stream>>>(x, gam, bet, h);

    dim3 cgrid(N_DIM / 64, C_DIM / 64, B_DIM);
    conv_kernel<false><<<cgrid, 256, 0, stream>>>(q_w, q_b, h, nullptr, qb);
    conv_kernel<false><<<cgrid, 256, 0, stream>>>(k_w, k_b, h, nullptr, kb);
    conv_kernel<false><<<cgrid, 256, 0, stream>>>(v_w, v_b, h, nullptr, vb);

    dim3 agrid(N_DIM / 64, B_DIM * NHEAD);
    attn_kernel<<<agrid, 256, 0, stream>>>(qb, kb, vb, at);

    conv_kernel<true><<<cgrid, 256, 0, stream>>>(p_w, p_b, at, x, out);
}

// Round 3
// 405.635 us; speedup vs baseline: 2.2426x; 2.2426x over previous
//
#include <hip/hip_runtime.h>
#include <hip/hip_bf16.h>
#include <math.h>

#define C_DIM 512
#define N_DIM 2048
#define B_DIM 4
#define NGRP 32
#define GCH 16          // channels per group
#define NHEAD 8
#define HDIM 64
#define EPSV 1e-6f

using f32x4  = __attribute__((ext_vector_type(4))) float;
using bf16x8 = __attribute__((ext_vector_type(8))) short;   // 8 bf16 raw bits (4 VGPRs)

static __device__ __forceinline__ unsigned short f2bf(float f) {
    union { __hip_bfloat16 h; unsigned short u; } cv;
    cv.h = __float2bfloat16(f);
    return cv.u;
}

// ---------------------------------------------------------------------------
// GroupNorm (unchanged)
// ---------------------------------------------------------------------------
__global__ __launch_bounds__(256) void gn_kernel(const float* __restrict__ x,
                                                 const float* __restrict__ gamma,
                                                 const float* __restrict__ beta,
                                                 float* __restrict__ h) {
    const int GSZ = GCH * N_DIM;            // 32768
    int bg = blockIdx.x;
    int b = bg / NGRP, g = bg % NGRP;
    size_t base = ((size_t)b * C_DIM + (size_t)g * GCH) * N_DIM;
    const float4* x4 = (const float4*)(x + base);
    float4* h4 = (float4*)(h + base);
    int tid = threadIdx.x;

    float s = 0.f, ss = 0.f;
    #pragma unroll
    for (int it = 0; it < GSZ / 4 / 256; ++it) {
        float4 v = x4[tid + it * 256];
        s  += v.x + v.y + v.z + v.w;
        ss += v.x * v.x + v.y * v.y + v.z * v.z + v.w * v.w;
    }
    __shared__ float rs[256], rss[256];
    rs[tid] = s; rss[tid] = ss;
    __syncthreads();
    for (int off = 128; off > 0; off >>= 1) {
        if (tid < off) { rs[tid] += rs[tid + off]; rss[tid] += rss[tid + off]; }
        __syncthreads();
    }
    float mean = rs[0] * (1.f / GSZ);
    float var  = rss[0] * (1.f / GSZ) - mean * mean;
    float rstd = rsqrtf(var + EPSV);

    #pragma unroll
    for (int it = 0; it < GSZ / 4 / 256; ++it) {
        int i4 = tid + it * 256;
        float4 v = x4[i4];
        int c = g * GCH + (i4 >> 9);
        float ga = gamma[c] * rstd;
        float be = beta[c] - mean * ga;
        v.x = v.x * ga + be;
        v.y = v.y * ga + be;
        v.z = v.z * ga + be;
        v.w = v.w * ga + be;
        h4[i4] = v;
    }
}

// ---------------------------------------------------------------------------
// Pointwise conv fp32 (unchanged)
// ---------------------------------------------------------------------------
template <bool RES>
__global__ __launch_bounds__(256) void conv_kernel(const float* __restrict__ W,
                                                   const float* __restrict__ bias,
                                                   const float* __restrict__ in,
                                                   const float* __restrict__ res,
                                                   float* __restrict__ out) {
    __shared__ float Ws[16][64];
    __shared__ float Hs[16][64];
    int bn = blockIdx.x * 64;
    int bo = blockIdx.y * 64;
    int b  = blockIdx.z;
    const float* inb = in + (size_t)b * C_DIM * N_DIM;
    int tid = threadIdx.x;
    int tx = tid & 15, ty = tid >> 4;

    float acc[4][4] = {};
    for (int k0 = 0; k0 < C_DIM; k0 += 16) {
        {
            int r = tid >> 2, c4 = (tid & 3) << 2;
            float4 w4 = *(const float4*)&W[(size_t)(bo + r) * C_DIM + k0 + c4];
            Ws[c4 + 0][r] = w4.x;
            Ws[c4 + 1][r] = w4.y;
            Ws[c4 + 2][r] = w4.z;
            Ws[c4 + 3][r] = w4.w;
        }
        {
            int rr = tid >> 4, cc4 = (tid & 15) << 2;
            *(float4*)&Hs[rr][cc4] =
                *(const float4*)&inb[(size_t)(k0 + rr) * N_DIM + bn + cc4];
        }
        __syncthreads();
        #pragma unroll
        for (int kk = 0; kk < 16; ++kk) {
            float4 a4 = *(const float4*)&Ws[kk][ty * 4];
            float4 b4 = *(const float4*)&Hs[kk][tx * 4];
            float a[4] = {a4.x, a4.y, a4.z, a4.w};
            float bv[4] = {b4.x, b4.y, b4.z, b4.w};
            #pragma unroll
            for (int i = 0; i < 4; ++i)
                #pragma unroll
                for (int j = 0; j < 4; ++j)
                    acc[i][j] = fmaf(a[i], bv[j], acc[i][j]);
        }
        __syncthreads();
    }
    #pragma unroll
    for (int i = 0; i < 4; ++i) {
        int o = bo + ty * 4 + i;
        float bi = bias[o];
        size_t off = ((size_t)b * C_DIM + o) * N_DIM + bn + tx * 4;
        float4 r4 = make_float4(0.f, 0.f, 0.f, 0.f);
        if (RES) r4 = *(const float4*)&res[off];
        float4 o4;
        o4.x = acc[i][0] + bi + r4.x;
        o4.y = acc[i][1] + bi + r4.y;
        o4.z = acc[i][2] + bi + r4.z;
        o4.w = acc[i][3] + bi + r4.w;
        *(float4*)&out[off] = o4;
    }
}

// ---------------------------------------------------------------------------
// pack_qk: fp32 [bh][d][n] head-slab -> bf16 [bh][n][d]  (transpose via LDS)
// ---------------------------------------------------------------------------
__global__ __launch_bounds__(256) void pack_qk_kernel(const float* __restrict__ src,
                                                      unsigned short* __restrict__ dst) {
    __shared__ unsigned short T[64 * 66];
    int nt = blockIdx.x;
    int bh = blockIdx.y;
    int tid = threadIdx.x;
    const float* s = src + (size_t)bh * HDIM * N_DIM + nt * 64;
    #pragma unroll
    for (int it = 0; it < 4; ++it) {
        int idx = tid + it * 256;
        int d = idx >> 4, n4 = (idx & 15) << 2;
        float4 v = *(const float4*)&s[(size_t)d * N_DIM + n4];
        T[(n4 + 0) * 66 + d] = f2bf(v.x);
        T[(n4 + 1) * 66 + d] = f2bf(v.y);
        T[(n4 + 2) * 66 + d] = f2bf(v.z);
        T[(n4 + 3) * 66 + d] = f2bf(v.w);
    }
    __syncthreads();
    unsigned short* dh = dst + ((size_t)bh * N_DIM + (size_t)nt * 64) * HDIM;
    #pragma unroll
    for (int it = 0; it < 2; ++it) {
        int idx = tid + it * 256;      // 0..511
        int n = idx >> 3, c8 = (idx & 7) * 8;
        bf16x8 o;
        #pragma unroll
        for (int e = 0; e < 8; ++e) o[e] = (short)T[n * 66 + c8 + e];
        *(bf16x8*)&dh[(size_t)n * HDIM + c8] = o;
    }
}

// ---------------------------------------------------------------------------
// pack_v: fp32 -> bf16, same layout. 8 elems/thread.
// ---------------------------------------------------------------------------
__global__ __launch_bounds__(256) void pack_v_kernel(const float* __restrict__ src,
                                                     unsigned short* __restrict__ dst) {
    size_t idx = (size_t)blockIdx.x * 256 + threadIdx.x;
    const float4* s4 = (const float4*)src;
    float4 a = s4[idx * 2], b = s4[idx * 2 + 1];
    bf16x8 o;
    o[0] = (short)f2bf(a.x); o[1] = (short)f2bf(a.y);
    o[2] = (short)f2bf(a.z); o[3] = (short)f2bf(a.w);
    o[4] = (short)f2bf(b.x); o[5] = (short)f2bf(b.y);
    o[6] = (short)f2bf(b.z); o[7] = (short)f2bf(b.w);
    *(bf16x8*)&dst[idx * 8] = o;
}

// ---------------------------------------------------------------------------
// MFMA bf16 flash attention. 4 waves/block; 64-query tile per block.
// Qt/Kt: bf16 [bh][n][d]; Vt: bf16 [bh][d][n]; out: fp32 [b][c][n].
// All 128B-row LDS tiles XOR-swizzled: byte ^= (row&7)<<4.
// ---------------------------------------------------------------------------
__global__ __launch_bounds__(256) void attn_kernel(const unsigned short* __restrict__ Qt,
                                                   const unsigned short* __restrict__ Kt,
                                                   const unsigned short* __restrict__ Vt,
                                                   float* __restrict__ out) {
    __shared__ char smem[32768];
    unsigned short* Qs = (unsigned short*)smem;            // 64 x 128B (swz)
    unsigned short* Ks = (unsigned short*)(smem + 8192);
    unsigned short* Vs = (unsigned short*)(smem + 16384);
    unsigned short* Ps = (unsigned short*)(smem + 24576);
    float* Otr = (float*)smem;                             // 64x64 f32, after loop

    int q0 = blockIdx.x * 64;
    int bh = blockIdx.y;
    int tid = threadIdx.x;
    int L = tid & 63, w = tid >> 6;
    int g = L >> 4, c = L & 15;

    const unsigned short* Qh = Qt + (size_t)bh * N_DIM * HDIM;
    const unsigned short* Kh = Kt + (size_t)bh * N_DIM * HDIM;
    const unsigned short* Vh = Vt + (size_t)bh * HDIM * N_DIM;

    // ---- stage Q tile (swizzled) ----
    #pragma unroll
    for (int it = 0; it < 2; ++it) {
        int idx = tid + it * 256;          // (row, 16B slot)
        int row = idx >> 3, sl = idx & 7;
        bf16x8 v = *(const bf16x8*)&Qh[(size_t)(q0 + row) * HDIM + sl * 8];
        *(bf16x8*)((char*)Qs + row * 128 + ((sl * 16) ^ ((row & 7) << 4))) = v;
    }
    __syncthreads();

    // ---- hoist Q fragments: A-frag row = w*16 + c, k = g*8 + j + 32*ks ----
    bf16x8 qf[2];
    {
        int row = w * 16 + c;
        #pragma unroll
        for (int ks = 0; ks < 2; ++ks)
            qf[ks] = *(const bf16x8*)((char*)Qs + row * 128 +
                                      ((g * 16 + ks * 64) ^ ((row & 7) << 4)));
    }

    f32x4 oacc[4];
    #pragma unroll
    for (int t = 0; t < 4; ++t) oacc[t] = f32x4{0.f, 0.f, 0.f, 0.f};
    float m_r[4], l_r[4];
    #pragma unroll
    for (int r = 0; r < 4; ++r) { m_r[r] = -INFINITY; l_r[r] = 0.f; }

    const float scale = 0.044194173824159216f;   // 512^-0.5

    for (int kt = 0; kt < N_DIM / 64; ++kt) {
        int k0 = kt * 64;
        // ---- stage K (k-pos rows, [k][d]) and V (d rows, [d][n]) swizzled ----
        #pragma unroll
        for (int i = 0; i < 2; ++i) {
            int ch = w * 2 + i;
            int row = ch * 8 + (L >> 3), sl = L & 7;
            bf16x8 kv = *(const bf16x8*)&Kh[(size_t)(k0 + row) * HDIM + sl * 8];
            bf16x8 vv = *(const bf16x8*)&Vh[(size_t)row * N_DIM + k0 + sl * 8];
            *(bf16x8*)((char*)Ks + row * 128 + ((sl * 16) ^ ((row & 7) << 4))) = kv;
            *(bf16x8*)((char*)Vs + row * 128 + ((sl * 16) ^ ((row & 7) << 4))) = vv;
        }
        __syncthreads();

        // ---- S = Q K^T : D[q=4g+r][kpos=16t+c] ----
        f32x4 sacc[4];
        #pragma unroll
        for (int t = 0; t < 4; ++t) sacc[t] = f32x4{0.f, 0.f, 0.f, 0.f};
        #pragma unroll
        for (int t = 0; t < 4; ++t) {
            int row = t * 16 + c;
            #pragma unroll
            for (int ks = 0; ks < 2; ++ks) {
                bf16x8 kf = *(const bf16x8*)((char*)Ks + row * 128 +
                                             ((g * 16 + ks * 64) ^ ((row & 7) << 4)));
                sacc[t] = __builtin_amdgcn_mfma_f32_16x16x32_bf16(qf[ks], kf, sacc[t], 0, 0, 0);
            }
        }

        // ---- online softmax (rows r live in lane group g; cols c reduce by shfl) ----
        float fac[4];
        #pragma unroll
        for (int r = 0; r < 4; ++r) {
            #pragma unroll
            for (int t = 0; t < 4; ++t) sacc[t][r] *= scale;
            float mt = fmaxf(fmaxf(sacc[0][r], sacc[1][r]), fmaxf(sacc[2][r], sacc[3][r]));
            mt = fmaxf(mt, __shfl_xor(mt, 1));
            mt = fmaxf(mt, __shfl_xor(mt, 2));
            mt = fmaxf(mt, __shfl_xor(mt, 4));
            mt = fmaxf(mt, __shfl_xor(mt, 8));
            float mn = fmaxf(m_r[r], mt);
            fac[r] = __expf(m_r[r] - mn);
            m_r[r] = mn;
            float rs = 0.f;
            #pragma unroll
            for (int t = 0; t < 4; ++t) {
                float p = __expf(sacc[t][r] - mn);
                sacc[t][r] = p;                      // reuse as P
                rs += p;
            }
            rs += __shfl_xor(rs, 1);
            rs += __shfl_xor(rs, 2);
            rs += __shfl_xor(rs, 4);
            rs += __shfl_xor(rs, 8);
            l_r[r] = l_r[r] * fac[r] + rs;
        }

        // ---- write P strip (wave-private rows w*16 .. w*16+15) as bf16 ----
        #pragma unroll
        for (int t = 0; t < 4; ++t)
            #pragma unroll
            for (int r = 0; r < 4; ++r) {
                int row = w * 16 + g * 4 + r;
                int colb = (t * 16 + c) * 2;
                *(unsigned short*)((char*)Ps + row * 128 +
                                   (colb ^ ((row & 7) << 4))) = f2bf(sacc[t][r]);
            }

        // ---- rescale O, then O += P V^T : D[q=4g+r][d=16t+c] ----
        #pragma unroll
        for (int t = 0; t < 4; ++t)
            #pragma unroll
            for (int r = 0; r < 4; ++r)
                oacc[t][r] *= fac[r];

        #pragma unroll
        for (int ks = 0; ks < 2; ++ks) {
            int prow = w * 16 + c;
            bf16x8 pf = *(const bf16x8*)((char*)Ps + prow * 128 +
                                         ((g * 16 + ks * 64) ^ ((prow & 7) << 4)));
            #pragma unroll
            for (int t = 0; t < 4; ++t) {
                int vrow = t * 16 + c;
                bf16x8 vf = *(const bf16x8*)((char*)Vs + vrow * 128 +
                                             ((g * 16 + ks * 64) ^ ((vrow & 7) << 4)));
                oacc[t] = __builtin_amdgcn_mfma_f32_16x16x32_bf16(pf, vf, oacc[t], 0, 0, 0);
            }
        }
        __syncthreads();
    }

    // ---- epilogue: O^T through LDS (swizzled cols), coalesced f32 store ----
    float linv[4];
    #pragma unroll
    for (int r = 0; r < 4; ++r) linv[r] = 1.f / l_r[r];
    #pragma unroll
    for (int t = 0; t < 4; ++t)
        #pragma unroll
        for (int r = 0; r < 4; ++r) {
            int d = t * 16 + c;
            int qn = w * 16 + g * 4 + r;
            Otr[d * 64 + (qn ^ ((d & 15) << 2))] = oacc[t][r] * linv[r];
        }
    __syncthreads();
    float* oh = out + (size_t)bh * HDIM * N_DIM;
    #pragma unroll
    for (int it = 0; it < 4; ++it) {
        int d = tid >> 2;
        int q4 = (tid & 3) * 16 + it * 4;
        int sw = (d & 15) << 2;
        float4 v = *(const float4*)&Otr[d * 64 + (q4 ^ sw)];
        *(float4*)&oh[(size_t)d * N_DIM + q0 + q4] = v;
    }
}

// ---------------------------------------------------------------------------
extern "C" void kernel_launch(void* const* d_in, const int* in_sizes, int n_in,
                              void* d_out, int out_size, void* d_ws, size_t ws_size,
                              hipStream_t stream) {
    (void)in_sizes; (void)n_in; (void)out_size; (void)ws_size;
    const float* x     = (const float*)d_in[0];
    const float* gam   = (const float*)d_in[1];
    const float* bet   = (const float*)d_in[2];
    const float* q_w   = (const float*)d_in[3];
    const float* q_b   = (const float*)d_in[4];
    const float* k_w   = (const float*)d_in[5];
    const float* k_b   = (const float*)d_in[6];
    const float* v_w   = (const float*)d_in[7];
    const float* v_b   = (const float*)d_in[8];
    const float* p_w   = (const float*)d_in[9];
    const float* p_b   = (const float*)d_in[10];
    float* out = (float*)d_out;

    // ---- workspace: 5 x 16MB fp32 regions (80 MB total, as round 1) ----
    const size_t SZ = (size_t)B_DIM * C_DIM * N_DIM;   // 4,194,304 elems
    float* wsf = (float*)d_ws;
    float* h  = wsf;               // 16 MB
    float* qb = wsf + SZ;          // 16 MB
    float* kb = wsf + 2 * SZ;      // 16 MB
    float* vb = wsf + 3 * SZ;      // 16 MB
    float* at = wsf + 4 * SZ;      // 16 MB
    // bf16 overlays on dead regions (each 8 MB = SZ shorts):
    unsigned short* Qt = (unsigned short*)h;             // h dead after convs
    unsigned short* Kt = (unsigned short*)(h + SZ / 2);  // second half of h region
    unsigned short* Vt = (unsigned short*)qb;            // qb dead after pack_qk(qb)

    gn_kernel<<<B_DIM * NGRP, 256, 0, stream>>>(x, gam, bet, h);

    dim3 cgrid(N_DIM / 64, C_DIM / 64, B_DIM);
    conv_kernel<false><<<cgrid, 256, 0, stream>>>(q_w, q_b, h, nullptr, qb);
    conv_kernel<false><<<cgrid, 256, 0, stream>>>(k_w, k_b, h, nullptr, kb);
    conv_kernel<false><<<cgrid, 256, 0, stream>>>(v_w, v_b, h, nullptr, vb);

    dim3 pgrid(N_DIM / 64, B_DIM * NHEAD);
    pack_qk_kernel<<<pgrid, 256, 0, stream>>>(qb, Qt);       // writes over h
    pack_qk_kernel<<<pgrid, 256, 0, stream>>>(kb, Kt);       // writes over h (2nd half)
    pack_v_kernel<<<(unsigned)(SZ / 8 / 256), 256, 0, stream>>>(vb, Vt);  // over qb

    dim3 agrid(N_DIM / 64, B_DIM * NHEAD);
    attn_kernel<<<agrid, 256, 0, stream>>>(Qt, Kt, Vt, at);

    conv_kernel<true><<<cgrid, 256, 0, stream>>>(p_w, p_b, at, x, out);
}

// Round 4
// 177.889 us; speedup vs baseline: 5.1136x; 2.2803x over previous
//
#include <hip/hip_runtime.h>
#include <hip/hip_bf16.h>
#include <math.h>

#define C_DIM 512
#define N_DIM 2048
#define B_DIM 4
#define NGRP 32
#define GCH 16          // channels per group
#define NHEAD 8
#define HDIM 64
#define EPSV 1e-6f

using f32x4  = __attribute__((ext_vector_type(4))) float;
using bf16x8 = __attribute__((ext_vector_type(8))) short;   // 8 bf16 raw bits (4 VGPRs)

// async global->LDS, 16B per lane; LDS dest = wave-uniform base + lane*16
#define GLL16(gp, lp) __builtin_amdgcn_global_load_lds( \
    (const __attribute__((address_space(1))) unsigned int*)(gp), \
    (__attribute__((address_space(3))) unsigned int*)(lp), 16, 0, 0)

static __device__ __forceinline__ unsigned short f2bf(float f) {
    union { __hip_bfloat16 h; unsigned short u; } cv;
    cv.h = __float2bfloat16(f);
    return cv.u;
}

// ---------------------------------------------------------------------------
// gn_stats: one block per (b,group); group slab contiguous (bg*32768 floats).
// stats[bg*2] = mean, stats[bg*2+1] = rstd
// ---------------------------------------------------------------------------
__global__ __launch_bounds__(256) void gn_stats(const float* __restrict__ x,
                                                float* __restrict__ stats) {
    const int GSZ = GCH * N_DIM;            // 32768
    int bg = blockIdx.x;
    const float4* x4 = (const float4*)(x + (size_t)bg * GSZ);
    int tid = threadIdx.x;

    float s = 0.f, ss = 0.f;
    #pragma unroll
    for (int it = 0; it < GSZ / 4 / 256; ++it) {
        float4 v = x4[tid + it * 256];
        s  += v.x + v.y + v.z + v.w;
        ss += v.x * v.x + v.y * v.y + v.z * v.z + v.w * v.w;
    }
    __shared__ float rs[256], rss[256];
    rs[tid] = s; rss[tid] = ss;
    __syncthreads();
    for (int off = 128; off > 0; off >>= 1) {
        if (tid < off) { rs[tid] += rs[tid + off]; rss[tid] += rss[tid + off]; }
        __syncthreads();
    }
    if (tid == 0) {
        float mean = rs[0] * (1.f / GSZ);
        float var  = rss[0] * (1.f / GSZ) - mean * mean;
        stats[bg * 2]     = mean;
        stats[bg * 2 + 1] = rsqrtf(var + EPSV);
    }
}

// ---------------------------------------------------------------------------
// gn_apply_t: x [b][c][n] fp32 -> ht [(b*n)][c] bf16 (normalized, transposed).
// 64x64 tiles through swizzled LDS. grid (N/64, C/64, B)
// ---------------------------------------------------------------------------
__global__ __launch_bounds__(256) void gn_apply_t(const float* __restrict__ x,
                                                  const float* __restrict__ stats,
                                                  const float* __restrict__ gamma,
                                                  const float* __restrict__ beta,
                                                  unsigned short* __restrict__ ht) {
    __shared__ char smem[8192];     // [64 n][64 c] bf16, rows 128B, XOR-swizzled
    int n0 = blockIdx.x * 64, c0 = blockIdx.y * 64, b = blockIdx.z;
    int tid = threadIdx.x;
    #pragma unroll
    for (int it = 0; it < 4; ++it) {
        int idx = tid + it * 256;
        int ci = idx >> 4, n4 = (idx & 15) << 2;
        int cg = c0 + ci, grp = cg >> 4;
        float mean = stats[(b * NGRP + grp) * 2];
        float rstd = stats[(b * NGRP + grp) * 2 + 1];
        float ga = gamma[cg] * rstd, be = beta[cg] - mean * ga;
        float4 v = *(const float4*)&x[((size_t)b * C_DIM + cg) * N_DIM + n0 + n4];
        float vals[4] = {v.x, v.y, v.z, v.w};
        #pragma unroll
        for (int j = 0; j < 4; ++j) {
            int nl = n4 + j;
            *(unsigned short*)(smem + nl * 128 + ((ci * 2) ^ ((nl & 7) << 4))) =
                f2bf(vals[j] * ga + be);
        }
    }
    __syncthreads();
    #pragma unroll
    for (int i = 0; i < 2; ++i) {
        int idx = tid + i * 256;       // 512 chunks = 64 rows x 8x16B
        int row = idx >> 3, ch = idx & 7;
        bf16x8 v = *(const bf16x8*)(smem + row * 128 + ((ch * 16) ^ ((row & 7) << 4)));
        *(bf16x8*)&ht[((size_t)(b * N_DIM + n0 + row)) * C_DIM + c0 + ch * 8] = v;
    }
}

// ---------------------------------------------------------------------------
// cast_bf16: fp32 -> bf16 raw, 8 elems/thread (for the 512x512 weights)
// ---------------------------------------------------------------------------
__global__ __launch_bounds__(256) void cast_bf16(const float* __restrict__ src,
                                                 unsigned short* __restrict__ dst) {
    size_t idx = (size_t)blockIdx.x * 256 + threadIdx.x;
    const float4* s4 = (const float4*)src;
    float4 a = s4[idx * 2], b = s4[idx * 2 + 1];
    bf16x8 o;
    o[0] = (short)f2bf(a.x); o[1] = (short)f2bf(a.y);
    o[2] = (short)f2bf(a.z); o[3] = (short)f2bf(a.w);
    o[4] = (short)f2bf(b.x); o[5] = (short)f2bf(b.y);
    o[6] = (short)f2bf(b.z); o[7] = (short)f2bf(b.w);
    *(bf16x8*)&dst[idx * 8] = o;
}

// ---------------------------------------------------------------------------
// conv_mfma: D[o][bn] = sum_c W[o][c] * ht[bn][c]  (+bias, modes below)
// Tile BM=64(o) x BN=128(bn) x BK=64. 4 waves, each 32x64.
// MODE 0: out bf16 natural [b][c][n]         (V conv)
// MODE 1: out bf16 [bh][n][d], *escale       (Q/K convs; one head per block)
// MODE 2: out fp32 [b][c][n] + res           (proj conv)
// ---------------------------------------------------------------------------
template <int MODE>
__global__ __launch_bounds__(256) void conv_mfma(const unsigned short* __restrict__ Wb,
                                                 const float* __restrict__ bias,
                                                 const unsigned short* __restrict__ Bsrc,
                                                 const float* __restrict__ res,
                                                 void* __restrict__ outp,
                                                 float escale) {
    __shared__ char smem[24576];
    unsigned short* As = (unsigned short*)smem;           // [64 o][64 k] swz, 8KB
    unsigned short* Bs = (unsigned short*)(smem + 8192);  // [128 n][64 k] swz, 16KB

    int bn0 = blockIdx.x * 128;      // flattened b*N + n
    int bo  = blockIdx.y * 64;
    int tid = threadIdx.x;
    int L = tid & 63, w = tid >> 6;
    int g = L >> 4, c = L & 15;
    int wr = w >> 1, wc = w & 1;

    f32x4 acc[2][4];
    #pragma unroll
    for (int t = 0; t < 2; ++t)
        #pragma unroll
        for (int u = 0; u < 4; ++u) acc[t][u] = f32x4{0.f, 0.f, 0.f, 0.f};

    for (int k0 = 0; k0 < C_DIM; k0 += 64) {
        // ---- stage A (8 x 1KB) and B (16 x 1KB), pre-swizzled source ----
        #pragma unroll
        for (int i = 0; i < 2; ++i) {
            int j = w * 2 + i;
            int ra = j * 8 + (L >> 3);
            int sl = (L & 7) ^ (ra & 7);
            GLL16(Wb + (size_t)(bo + ra) * C_DIM + k0 + sl * 8, (char*)As + j * 1024);
        }
        #pragma unroll
        for (int i = 0; i < 4; ++i) {
            int j = w * 4 + i;
            int rb = j * 8 + (L >> 3);
            int sl = (L & 7) ^ (rb & 7);
            GLL16(Bsrc + (size_t)(bn0 + rb) * C_DIM + k0 + sl * 8, (char*)Bs + j * 1024);
        }
        __syncthreads();

        bf16x8 af[2][2], bfr[4][2];
        #pragma unroll
        for (int t = 0; t < 2; ++t) {
            int row = wr * 32 + t * 16 + c;
            #pragma unroll
            for (int ks = 0; ks < 2; ++ks)
                af[t][ks] = *(const bf16x8*)((char*)As + row * 128 +
                                             ((g * 16 + ks * 64) ^ ((row & 7) << 4)));
        }
        #pragma unroll
        for (int u = 0; u < 4; ++u) {
            int row = wc * 64 + u * 16 + c;
            #pragma unroll
            for (int ks = 0; ks < 2; ++ks)
                bfr[u][ks] = *(const bf16x8*)((char*)Bs + row * 128 +
                                              ((g * 16 + ks * 64) ^ ((row & 7) << 4)));
        }
        #pragma unroll
        for (int ks = 0; ks < 2; ++ks)
            #pragma unroll
            for (int t = 0; t < 2; ++t)
                #pragma unroll
                for (int u = 0; u < 4; ++u)
                    acc[t][u] = __builtin_amdgcn_mfma_f32_16x16x32_bf16(
                        af[t][ks], bfr[u][ks], acc[t][u], 0, 0, 0);
        __syncthreads();
    }

    int b  = bn0 >> 11;              // N_DIM = 2048
    int nb = bn0 & (N_DIM - 1);

    if (MODE == 0) {
        unsigned short* vt = (unsigned short*)outp;
        #pragma unroll
        for (int t = 0; t < 2; ++t)
            #pragma unroll
            for (int r = 0; r < 4; ++r) {
                int m = bo + wr * 32 + t * 16 + g * 4 + r;
                float bi = bias[m];
                #pragma unroll
                for (int u = 0; u < 4; ++u) {
                    int n = nb + wc * 64 + u * 16 + c;
                    vt[((size_t)b * C_DIM + m) * N_DIM + n] = f2bf(acc[t][u][r] + bi);
                }
            }
    } else if (MODE == 1) {
        int hh = bo >> 6;            // BM=64 => one head per block
        int bh = b * NHEAD + hh;
        unsigned short* Ts = (unsigned short*)smem;   // [128 n][64 d] swz, 16KB
        #pragma unroll
        for (int t = 0; t < 2; ++t)
            #pragma unroll
            for (int r = 0; r < 4; ++r) {
                int ml = wr * 32 + t * 16 + g * 4 + r;   // d
                float bi = bias[bo + ml];
                #pragma unroll
                for (int u = 0; u < 4; ++u) {
                    int nl = wc * 64 + u * 16 + c;
                    *(unsigned short*)((char*)Ts + nl * 128 + ((ml * 2) ^ ((nl & 7) << 4))) =
                        f2bf((acc[t][u][r] + bi) * escale);
                }
            }
        __syncthreads();
        unsigned short* qt = (unsigned short*)outp;
        #pragma unroll
        for (int i = 0; i < 4; ++i) {
            int idx = tid + i * 256;     // 1024 chunks = 128 rows x 8x16B
            int row = idx >> 3, ch = idx & 7;
            bf16x8 v = *(const bf16x8*)((char*)Ts + row * 128 + ((ch * 16) ^ ((row & 7) << 4)));
            *(bf16x8*)&qt[((size_t)bh * N_DIM + nb + row) * HDIM + ch * 8] = v;
        }
    } else {
        float* outf = (float*)outp;
        #pragma unroll
        for (int t = 0; t < 2; ++t)
            #pragma unroll
            for (int r = 0; r < 4; ++r) {
                int m = bo + wr * 32 + t * 16 + g * 4 + r;
                float bi = bias[m];
                #pragma unroll
                for (int u = 0; u < 4; ++u) {
                    int n = nb + wc * 64 + u * 16 + c;
                    size_t off = ((size_t)b * C_DIM + m) * N_DIM + n;
                    outf[off] = acc[t][u][r] + bi + res[off];
                }
            }
    }
}

// ---------------------------------------------------------------------------
// MFMA bf16 flash attention. Q pre-scaled by scale*log2e -> exp2-domain softmax.
// Qt/Kt: bf16 [bh][n][d]; Vt: bf16 [b][c][n] (== [bh][d][n]); at: bf16 [b][n][c].
// ---------------------------------------------------------------------------
__global__ __launch_bounds__(256) void attn_kernel(const unsigned short* __restrict__ Qt,
                                                   const unsigned short* __restrict__ Kt,
                                                   const unsigned short* __restrict__ Vt,
                                                   unsigned short* __restrict__ at) {
    __shared__ char smem[32768];
    unsigned short* Qs = (unsigned short*)smem;            // 64 x 128B (swz)
    unsigned short* Ks = (unsigned short*)(smem + 8192);
    unsigned short* Vs = (unsigned short*)(smem + 16384);
    unsigned short* Ps = (unsigned short*)(smem + 24576);

    int q0 = blockIdx.x * 64;
    int bh = blockIdx.y;
    int b = bh >> 3, hh = bh & 7;
    int tid = threadIdx.x;
    int L = tid & 63, w = tid >> 6;
    int g = L >> 4, c = L & 15;

    const unsigned short* Qh = Qt + (size_t)bh * N_DIM * HDIM;
    const unsigned short* Kh = Kt + (size_t)bh * N_DIM * HDIM;
    const unsigned short* Vh = Vt + (size_t)bh * HDIM * N_DIM;

    #pragma unroll
    for (int it = 0; it < 2; ++it) {
        int idx = tid + it * 256;
        int row = idx >> 3, sl = idx & 7;
        bf16x8 v = *(const bf16x8*)&Qh[(size_t)(q0 + row) * HDIM + sl * 8];
        *(bf16x8*)((char*)Qs + row * 128 + ((sl * 16) ^ ((row & 7) << 4))) = v;
    }
    __syncthreads();

    bf16x8 qf[2];
    {
        int row = w * 16 + c;
        #pragma unroll
        for (int ks = 0; ks < 2; ++ks)
            qf[ks] = *(const bf16x8*)((char*)Qs + row * 128 +
                                      ((g * 16 + ks * 64) ^ ((row & 7) << 4)));
    }

    f32x4 oacc[4];
    #pragma unroll
    for (int t = 0; t < 4; ++t) oacc[t] = f32x4{0.f, 0.f, 0.f, 0.f};
    float m_r[4], l_r[4];
    #pragma unroll
    for (int r = 0; r < 4; ++r) { m_r[r] = -INFINITY; l_r[r] = 0.f; }

    for (int kt = 0; kt < N_DIM / 64; ++kt) {
        int k0 = kt * 64;
        #pragma unroll
        for (int i = 0; i < 2; ++i) {
            int ch = w * 2 + i;
            int row = ch * 8 + (L >> 3), sl = L & 7;
            bf16x8 kv = *(const bf16x8*)&Kh[(size_t)(k0 + row) * HDIM + sl * 8];
            bf16x8 vv = *(const bf16x8*)&Vh[(size_t)row * N_DIM + k0 + sl * 8];
            *(bf16x8*)((char*)Ks + row * 128 + ((sl * 16) ^ ((row & 7) << 4))) = kv;
            *(bf16x8*)((char*)Vs + row * 128 + ((sl * 16) ^ ((row & 7) << 4))) = vv;
        }
        __syncthreads();

        // S = Q K^T (already includes scale*log2e via Q)
        f32x4 sacc[4];
        #pragma unroll
        for (int t = 0; t < 4; ++t) sacc[t] = f32x4{0.f, 0.f, 0.f, 0.f};
        #pragma unroll
        for (int t = 0; t < 4; ++t) {
            int row = t * 16 + c;
            #pragma unroll
            for (int ks = 0; ks < 2; ++ks) {
                bf16x8 kf = *(const bf16x8*)((char*)Ks + row * 128 +
                                             ((g * 16 + ks * 64) ^ ((row & 7) << 4)));
                sacc[t] = __builtin_amdgcn_mfma_f32_16x16x32_bf16(qf[ks], kf, sacc[t], 0, 0, 0);
            }
        }

        // online softmax in log2 domain
        float fac[4];
        #pragma unroll
        for (int r = 0; r < 4; ++r) {
            float mt = fmaxf(fmaxf(sacc[0][r], sacc[1][r]), fmaxf(sacc[2][r], sacc[3][r]));
            mt = fmaxf(mt, __shfl_xor(mt, 1));
            mt = fmaxf(mt, __shfl_xor(mt, 2));
            mt = fmaxf(mt, __shfl_xor(mt, 4));
            mt = fmaxf(mt, __shfl_xor(mt, 8));
            float mn = fmaxf(m_r[r], mt);
            fac[r] = exp2f(m_r[r] - mn);
            m_r[r] = mn;
            float rs = 0.f;
            #pragma unroll
            for (int t = 0; t < 4; ++t) {
                float p = exp2f(sacc[t][r] - mn);
                sacc[t][r] = p;
                rs += p;
            }
            rs += __shfl_xor(rs, 1);
            rs += __shfl_xor(rs, 2);
            rs += __shfl_xor(rs, 4);
            rs += __shfl_xor(rs, 8);
            l_r[r] = l_r[r] * fac[r] + rs;
        }

        // P strip (wave-private rows) bf16
        #pragma unroll
        for (int t = 0; t < 4; ++t)
            #pragma unroll
            for (int r = 0; r < 4; ++r) {
                int row = w * 16 + g * 4 + r;
                int colb = (t * 16 + c) * 2;
                *(unsigned short*)((char*)Ps + row * 128 +
                                   (colb ^ ((row & 7) << 4))) = f2bf(sacc[t][r]);
            }

        #pragma unroll
        for (int t = 0; t < 4; ++t)
            #pragma unroll
            for (int r = 0; r < 4; ++r)
                oacc[t][r] *= fac[r];

        #pragma unroll
        for (int ks = 0; ks < 2; ++ks) {
            int prow = w * 16 + c;
            bf16x8 pf = *(const bf16x8*)((char*)Ps + prow * 128 +
                                         ((g * 16 + ks * 64) ^ ((prow & 7) << 4)));
            #pragma unroll
            for (int t = 0; t < 4; ++t) {
                int vrow = t * 16 + c;
                bf16x8 vf = *(const bf16x8*)((char*)Vs + vrow * 128 +
                                             ((g * 16 + ks * 64) ^ ((vrow & 7) << 4)));
                oacc[t] = __builtin_amdgcn_mfma_f32_16x16x32_bf16(pf, vf, oacc[t], 0, 0, 0);
            }
        }
        __syncthreads();
    }

    // epilogue: O [q][d] bf16 swizzled in LDS, then [b][n][c] global
    float linv[4];
    #pragma unroll
    for (int r = 0; r < 4; ++r) linv[r] = 1.f / l_r[r];
    #pragma unroll
    for (int t = 0; t < 4; ++t)
        #pragma unroll
        for (int r = 0; r < 4; ++r) {
            int d = t * 16 + c;
            int qn = w * 16 + g * 4 + r;
            *(unsigned short*)(smem + qn * 128 + ((d * 2) ^ ((qn & 7) << 4))) =
                f2bf(oacc[t][r] * linv[r]);
        }
    __syncthreads();
    #pragma unroll
    for (int i = 0; i < 2; ++i) {
        int idx = tid + i * 256;       // 512 chunks = 64 rows x 8x16B
        int row = idx >> 3, ch = idx & 7;
        bf16x8 v = *(const bf16x8*)(smem + row * 128 + ((ch * 16) ^ ((row & 7) << 4)));
        *(bf16x8*)&at[((size_t)(b * N_DIM + q0 + row)) * C_DIM + hh * HDIM + ch * 8] = v;
    }
}

// ---------------------------------------------------------------------------
extern "C" void kernel_launch(void* const* d_in, const int* in_sizes, int n_in,
                              void* d_out, int out_size, void* d_ws, size_t ws_size,
                              hipStream_t stream) {
    (void)in_sizes; (void)n_in; (void)out_size; (void)ws_size;
    const float* x     = (const float*)d_in[0];
    const float* gam   = (const float*)d_in[1];
    const float* bet   = (const float*)d_in[2];
    const float* q_w   = (const float*)d_in[3];
    const float* q_b   = (const float*)d_in[4];
    const float* k_w   = (const float*)d_in[5];
    const float* k_b   = (const float*)d_in[6];
    const float* v_w   = (const float*)d_in[7];
    const float* v_b   = (const float*)d_in[8];
    const float* p_w   = (const float*)d_in[9];
    const float* p_b   = (const float*)d_in[10];
    float* out = (float*)d_out;

    const size_t MB = 1 << 20;
    char* wsb = (char*)d_ws;
    unsigned short* ht  = (unsigned short*)(wsb);              // 8 MB  [8192][512]
    unsigned short* wqb = (unsigned short*)(wsb + 8 * MB);     // 512KB each
    unsigned short* wkb = (unsigned short*)(wsb + 8 * MB + 512 * 1024);
    unsigned short* wvb = (unsigned short*)(wsb + 9 * MB);
    unsigned short* wpb = (unsigned short*)(wsb + 9 * MB + 512 * 1024);
    float*          stats = (float*)(wsb + 10 * MB);           // 1 KB
    unsigned short* qt  = (unsigned short*)(wsb + 11 * MB);    // 8 MB [bh][n][d]
    unsigned short* kt  = (unsigned short*)(wsb + 19 * MB);    // 8 MB
    unsigned short* vt  = (unsigned short*)(wsb + 27 * MB);    // 8 MB [b][c][n]
    unsigned short* at  = (unsigned short*)(wsb + 35 * MB);    // 8 MB [b][n][c]

    gn_stats<<<B_DIM * NGRP, 256, 0, stream>>>(x, stats);
    gn_apply_t<<<dim3(N_DIM / 64, C_DIM / 64, B_DIM), 256, 0, stream>>>(x, stats, gam, bet, ht);

    cast_bf16<<<128, 256, 0, stream>>>(q_w, wqb);
    cast_bf16<<<128, 256, 0, stream>>>(k_w, wkb);
    cast_bf16<<<128, 256, 0, stream>>>(v_w, wvb);
    cast_bf16<<<128, 256, 0, stream>>>(p_w, wpb);

    const float escale = 0.044194173824159216f * 1.4426950408889634f;  // scale*log2(e)
    dim3 cgrid(B_DIM * N_DIM / 128, C_DIM / 64);
    conv_mfma<1><<<cgrid, 256, 0, stream>>>(wqb, q_b, ht, nullptr, qt, escale);
    conv_mfma<1><<<cgrid, 256, 0, stream>>>(wkb, k_b, ht, nullptr, kt, 1.0f);
    conv_mfma<0><<<cgrid, 256, 0, stream>>>(wvb, v_b, ht, nullptr, vt, 1.0f);

    attn_kernel<<<dim3(N_DIM / 64, B_DIM * NHEAD), 256, 0, stream>>>(qt, kt, vt, at);

    conv_mfma<2><<<cgrid, 256, 0, stream>>>(wpb, p_b, at, x, out, 1.0f);
}

// Round 5
// 176.764 us; speedup vs baseline: 5.1462x; 1.0064x over previous
//
#include <hip/hip_runtime.h>
#include <hip/hip_bf16.h>
#include <math.h>

#define C_DIM 512
#define N_DIM 2048
#define B_DIM 4
#define NGRP 32
#define GCH 16          // channels per group
#define NHEAD 8
#define HDIM 64
#define EPSV 1e-6f

using f32x4  = __attribute__((ext_vector_type(4))) float;
using bf16x8 = __attribute__((ext_vector_type(8))) short;   // 8 bf16 raw bits (4 VGPRs)

// async global->LDS, 16B per lane; LDS dest = wave-uniform base + lane*16
#define GLL16(gp, lp) __builtin_amdgcn_global_load_lds( \
    (const __attribute__((address_space(1))) unsigned int*)(gp), \
    (__attribute__((address_space(3))) unsigned int*)(lp), 16, 0, 0)

static __device__ __forceinline__ unsigned short f2bf(float f) {
    union { __hip_bfloat16 h; unsigned short u; } cv;
    cv.h = __float2bfloat16(f);
    return cv.u;
}

// ---------------------------------------------------------------------------
// gn_stats: one block per (b,group); group slab contiguous (bg*32768 floats).
// ---------------------------------------------------------------------------
__global__ __launch_bounds__(256) void gn_stats(const float* __restrict__ x,
                                                float* __restrict__ stats) {
    const int GSZ = GCH * N_DIM;            // 32768
    int bg = blockIdx.x;
    const float4* x4 = (const float4*)(x + (size_t)bg * GSZ);
    int tid = threadIdx.x;

    float s = 0.f, ss = 0.f;
    #pragma unroll
    for (int it = 0; it < GSZ / 4 / 256; ++it) {
        float4 v = x4[tid + it * 256];
        s  += v.x + v.y + v.z + v.w;
        ss += v.x * v.x + v.y * v.y + v.z * v.z + v.w * v.w;
    }
    __shared__ float rs[256], rss[256];
    rs[tid] = s; rss[tid] = ss;
    __syncthreads();
    for (int off = 128; off > 0; off >>= 1) {
        if (tid < off) { rs[tid] += rs[tid + off]; rss[tid] += rss[tid + off]; }
        __syncthreads();
    }
    if (tid == 0) {
        float mean = rs[0] * (1.f / GSZ);
        float var  = rss[0] * (1.f / GSZ) - mean * mean;
        stats[bg * 2]     = mean;
        stats[bg * 2 + 1] = rsqrtf(var + EPSV);
    }
}

// ---------------------------------------------------------------------------
// gn_apply_t: x [b][c][n] fp32 -> ht [(b*n)][c] bf16 (normalized, transposed).
// ---------------------------------------------------------------------------
__global__ __launch_bounds__(256) void gn_apply_t(const float* __restrict__ x,
                                                  const float* __restrict__ stats,
                                                  const float* __restrict__ gamma,
                                                  const float* __restrict__ beta,
                                                  unsigned short* __restrict__ ht) {
    __shared__ char smem[8192];     // [64 n][64 c] bf16, rows 128B, XOR-swizzled
    int n0 = blockIdx.x * 64, c0 = blockIdx.y * 64, b = blockIdx.z;
    int tid = threadIdx.x;
    #pragma unroll
    for (int it = 0; it < 4; ++it) {
        int idx = tid + it * 256;
        int ci = idx >> 4, n4 = (idx & 15) << 2;
        int cg = c0 + ci, grp = cg >> 4;
        float mean = stats[(b * NGRP + grp) * 2];
        float rstd = stats[(b * NGRP + grp) * 2 + 1];
        float ga = gamma[cg] * rstd, be = beta[cg] - mean * ga;
        float4 v = *(const float4*)&x[((size_t)b * C_DIM + cg) * N_DIM + n0 + n4];
        float vals[4] = {v.x, v.y, v.z, v.w};
        #pragma unroll
        for (int j = 0; j < 4; ++j) {
            int nl = n4 + j;
            *(unsigned short*)(smem + nl * 128 + ((ci * 2) ^ ((nl & 7) << 4))) =
                f2bf(vals[j] * ga + be);
        }
    }
    __syncthreads();
    #pragma unroll
    for (int i = 0; i < 2; ++i) {
        int idx = tid + i * 256;       // 512 chunks = 64 rows x 8x16B
        int row = idx >> 3, ch = idx & 7;
        bf16x8 v = *(const bf16x8*)(smem + row * 128 + ((ch * 16) ^ ((row & 7) << 4)));
        *(bf16x8*)&ht[((size_t)(b * N_DIM + n0 + row)) * C_DIM + c0 + ch * 8] = v;
    }
}

// ---------------------------------------------------------------------------
// cast_bf16: fp32 -> bf16 raw, 8 elems/thread
// ---------------------------------------------------------------------------
__global__ __launch_bounds__(256) void cast_bf16(const float* __restrict__ src,
                                                 unsigned short* __restrict__ dst) {
    size_t idx = (size_t)blockIdx.x * 256 + threadIdx.x;
    const float4* s4 = (const float4*)src;
    float4 a = s4[idx * 2], b = s4[idx * 2 + 1];
    bf16x8 o;
    o[0] = (short)f2bf(a.x); o[1] = (short)f2bf(a.y);
    o[2] = (short)f2bf(a.z); o[3] = (short)f2bf(a.w);
    o[4] = (short)f2bf(b.x); o[5] = (short)f2bf(b.y);
    o[6] = (short)f2bf(b.z); o[7] = (short)f2bf(b.w);
    *(bf16x8*)&dst[idx * 8] = o;
}

// ---------------------------------------------------------------------------
// conv_mfma: D[o][bn] = sum_c W[o][c] * ht[bn][c]  (+bias, modes below)
// Tile BM=64(o) x BN=128(bn) x BK=64. 4 waves, each 32x64.
// MODE 0: out bf16 natural [b][c][n]         (V conv)
// MODE 1: out bf16 [bh][n][d], *escale       (Q/K convs; one head per block)
// MODE 2: out fp32 [b][c][n] + res           (proj conv)
// ---------------------------------------------------------------------------
template <int MODE>
__global__ __launch_bounds__(256) void conv_mfma(const unsigned short* __restrict__ Wb,
                                                 const float* __restrict__ bias,
                                                 const unsigned short* __restrict__ Bsrc,
                                                 const float* __restrict__ res,
                                                 void* __restrict__ outp,
                                                 float escale) {
    __shared__ char smem[24576];
    unsigned short* As = (unsigned short*)smem;           // [64 o][64 k] swz, 8KB
    unsigned short* Bs = (unsigned short*)(smem + 8192);  // [128 n][64 k] swz, 16KB

    int bn0 = blockIdx.x * 128;      // flattened b*N + n
    int bo  = blockIdx.y * 64;
    int tid = threadIdx.x;
    int L = tid & 63, w = tid >> 6;
    int g = L >> 4, c = L & 15;
    int wr = w >> 1, wc = w & 1;

    f32x4 acc[2][4];
    #pragma unroll
    for (int t = 0; t < 2; ++t)
        #pragma unroll
        for (int u = 0; u < 4; ++u) acc[t][u] = f32x4{0.f, 0.f, 0.f, 0.f};

    for (int k0 = 0; k0 < C_DIM; k0 += 64) {
        #pragma unroll
        for (int i = 0; i < 2; ++i) {
            int j = w * 2 + i;
            int ra = j * 8 + (L >> 3);
            int sl = (L & 7) ^ (ra & 7);
            GLL16(Wb + (size_t)(bo + ra) * C_DIM + k0 + sl * 8, (char*)As + j * 1024);
        }
        #pragma unroll
        for (int i = 0; i < 4; ++i) {
            int j = w * 4 + i;
            int rb = j * 8 + (L >> 3);
            int sl = (L & 7) ^ (rb & 7);
            GLL16(Bsrc + (size_t)(bn0 + rb) * C_DIM + k0 + sl * 8, (char*)Bs + j * 1024);
        }
        __syncthreads();

        bf16x8 af[2][2], bfr[4][2];
        #pragma unroll
        for (int t = 0; t < 2; ++t) {
            int row = wr * 32 + t * 16 + c;
            #pragma unroll
            for (int ks = 0; ks < 2; ++ks)
                af[t][ks] = *(const bf16x8*)((char*)As + row * 128 +
                                             ((g * 16 + ks * 64) ^ ((row & 7) << 4)));
        }
        #pragma unroll
        for (int u = 0; u < 4; ++u) {
            int row = wc * 64 + u * 16 + c;
            #pragma unroll
            for (int ks = 0; ks < 2; ++ks)
                bfr[u][ks] = *(const bf16x8*)((char*)Bs + row * 128 +
                                              ((g * 16 + ks * 64) ^ ((row & 7) << 4)));
        }
        #pragma unroll
        for (int ks = 0; ks < 2; ++ks)
            #pragma unroll
            for (int t = 0; t < 2; ++t)
                #pragma unroll
                for (int u = 0; u < 4; ++u)
                    acc[t][u] = __builtin_amdgcn_mfma_f32_16x16x32_bf16(
                        af[t][ks], bfr[u][ks], acc[t][u], 0, 0, 0);
        __syncthreads();
    }

    int b  = bn0 >> 11;              // N_DIM = 2048
    int nb = bn0 & (N_DIM - 1);

    if (MODE == 0) {
        unsigned short* vt = (unsigned short*)outp;
        #pragma unroll
        for (int t = 0; t < 2; ++t)
            #pragma unroll
            for (int r = 0; r < 4; ++r) {
                int m = bo + wr * 32 + t * 16 + g * 4 + r;
                float bi = bias[m];
                #pragma unroll
                for (int u = 0; u < 4; ++u) {
                    int n = nb + wc * 64 + u * 16 + c;
                    vt[((size_t)b * C_DIM + m) * N_DIM + n] = f2bf(acc[t][u][r] + bi);
                }
            }
    } else if (MODE == 1) {
        int hh = bo >> 6;            // BM=64 => one head per block
        int bh = b * NHEAD + hh;
        unsigned short* Ts = (unsigned short*)smem;   // [128 n][64 d] swz, 16KB
        __syncthreads();
        #pragma unroll
        for (int t = 0; t < 2; ++t)
            #pragma unroll
            for (int r = 0; r < 4; ++r) {
                int ml = wr * 32 + t * 16 + g * 4 + r;   // d
                float bi = bias[bo + ml];
                #pragma unroll
                for (int u = 0; u < 4; ++u) {
                    int nl = wc * 64 + u * 16 + c;
                    *(unsigned short*)((char*)Ts + nl * 128 + ((ml * 2) ^ ((nl & 7) << 4))) =
                        f2bf((acc[t][u][r] + bi) * escale);
                }
            }
        __syncthreads();
        unsigned short* qt = (unsigned short*)outp;
        #pragma unroll
        for (int i = 0; i < 4; ++i) {
            int idx = tid + i * 256;     // 1024 chunks = 128 rows x 8x16B
            int row = idx >> 3, ch = idx & 7;
            bf16x8 v = *(const bf16x8*)((char*)Ts + row * 128 + ((ch * 16) ^ ((row & 7) << 4)));
            *(bf16x8*)&qt[((size_t)bh * N_DIM + nb + row) * HDIM + ch * 8] = v;
        }
    } else {
        float* outf = (float*)outp;
        #pragma unroll
        for (int t = 0; t < 2; ++t)
            #pragma unroll
            for (int r = 0; r < 4; ++r) {
                int m = bo + wr * 32 + t * 16 + g * 4 + r;
                float bi = bias[m];
                #pragma unroll
                for (int u = 0; u < 4; ++u) {
                    int n = nb + wc * 64 + u * 16 + c;
                    size_t off = ((size_t)b * C_DIM + m) * N_DIM + n;
                    outf[off] = acc[t][u][r] + bi + res[off];
                }
            }
    }
}

// ---------------------------------------------------------------------------
// attn iteration body. CUR/NXT = static register-buffer indices (rule #20).
// T14: K/V for tile kt already in regs; write them to LDS, then issue kt+1
// loads; latency hides under this iter's MFMA+softmax.
// ---------------------------------------------------------------------------
template <int CUR>
__device__ __forceinline__ void attn_iter(
    int kt, int L, int w, int g, int c,
    const unsigned short* __restrict__ Kh, const unsigned short* __restrict__ Vh,
    const int rowi[2], const int ldsoff[2],
    char* Ks, char* Vs, char* Ps,
    const bf16x8 qf[2], bf16x8 (&kreg)[2][2], bf16x8 (&vreg)[2][2],
    f32x4 (&oacc)[4], float (&m_r)[4], float (&l_r)[4])
{
    const int NXT = CUR ^ 1;
    __syncthreads();                 // prev iter's Ks/Vs reads done
    #pragma unroll
    for (int i = 0; i < 2; ++i) {
        *(bf16x8*)(Ks + ldsoff[i]) = kreg[CUR][i];
        *(bf16x8*)(Vs + ldsoff[i]) = vreg[CUR][i];
    }
    if (kt < N_DIM / 64 - 1) {       // issue next tile's loads (T14)
        int k0n = (kt + 1) * 64;
        #pragma unroll
        for (int i = 0; i < 2; ++i) {
            kreg[NXT][i] = *(const bf16x8*)&Kh[(size_t)(k0n + rowi[i]) * HDIM + (L & 7) * 8];
            vreg[NXT][i] = *(const bf16x8*)&Vh[(size_t)rowi[i] * N_DIM + k0n + (L & 7) * 8];
        }
    }
    __syncthreads();                 // Ks/Vs visible to all waves

    // ---- S = Q K^T : D[q=4g+r][kpos=16t+c] ----
    f32x4 sacc[4];
    #pragma unroll
    for (int t = 0; t < 4; ++t) sacc[t] = f32x4{0.f, 0.f, 0.f, 0.f};
    __builtin_amdgcn_s_setprio(1);
    #pragma unroll
    for (int t = 0; t < 4; ++t) {
        int row = t * 16 + c;
        #pragma unroll
        for (int ks = 0; ks < 2; ++ks) {
            bf16x8 kf = *(const bf16x8*)(Ks + row * 128 +
                                         ((g * 16 + ks * 64) ^ ((row & 7) << 4)));
            sacc[t] = __builtin_amdgcn_mfma_f32_16x16x32_bf16(qf[ks], kf, sacc[t], 0, 0, 0);
        }
    }
    __builtin_amdgcn_s_setprio(0);

    // ---- online softmax (exp2 domain), T13 defer-max ----
    float mtv[4];
    #pragma unroll
    for (int r = 0; r < 4; ++r) {
        float mt = fmaxf(fmaxf(sacc[0][r], sacc[1][r]), fmaxf(sacc[2][r], sacc[3][r]));
        mt = fmaxf(mt, __shfl_xor(mt, 1));
        mt = fmaxf(mt, __shfl_xor(mt, 2));
        mt = fmaxf(mt, __shfl_xor(mt, 4));
        mt = fmaxf(mt, __shfl_xor(mt, 8));
        mtv[r] = mt;
    }
    float growth = fmaxf(fmaxf(mtv[0] - m_r[0], mtv[1] - m_r[1]),
                         fmaxf(mtv[2] - m_r[2], mtv[3] - m_r[3]));
    if (!__all(growth <= 6.0f)) {    // rescale only when max actually grew
        #pragma unroll
        for (int r = 0; r < 4; ++r) {
            float mn = fmaxf(m_r[r], mtv[r]);
            float fac = exp2f(m_r[r] - mn);
            m_r[r] = mn;
            l_r[r] *= fac;
            #pragma unroll
            for (int t = 0; t < 4; ++t) oacc[t][r] *= fac;
        }
    }
    #pragma unroll
    for (int r = 0; r < 4; ++r) {
        float rs = 0.f;
        #pragma unroll
        for (int t = 0; t < 4; ++t) {
            float p = exp2f(sacc[t][r] - m_r[r]);
            sacc[t][r] = p;
            rs += p;
        }
        rs += __shfl_xor(rs, 1);
        rs += __shfl_xor(rs, 2);
        rs += __shfl_xor(rs, 4);
        rs += __shfl_xor(rs, 8);
        l_r[r] += rs;
    }

    // ---- P strip (wave-private rows w*16..w*16+15) bf16 ----
    #pragma unroll
    for (int t = 0; t < 4; ++t)
        #pragma unroll
        for (int r = 0; r < 4; ++r) {
            int row = w * 16 + g * 4 + r;
            int colb = (t * 16 + c) * 2;
            *(unsigned short*)(Ps + row * 128 + (colb ^ ((row & 7) << 4))) = f2bf(sacc[t][r]);
        }

    // ---- O += P V^T : D[q=4g+r][d=16t+c] ----
    __builtin_amdgcn_s_setprio(1);
    #pragma unroll
    for (int ks = 0; ks < 2; ++ks) {
        int prow = w * 16 + c;
        bf16x8 pf = *(const bf16x8*)(Ps + prow * 128 +
                                     ((g * 16 + ks * 64) ^ ((prow & 7) << 4)));
        #pragma unroll
        for (int t = 0; t < 4; ++t) {
            int vrow = t * 16 + c;
            bf16x8 vf = *(const bf16x8*)(Vs + vrow * 128 +
                                         ((g * 16 + ks * 64) ^ ((vrow & 7) << 4)));
            oacc[t] = __builtin_amdgcn_mfma_f32_16x16x32_bf16(pf, vf, oacc[t], 0, 0, 0);
        }
    }
    __builtin_amdgcn_s_setprio(0);
}

// ---------------------------------------------------------------------------
// MFMA bf16 flash attention. Q pre-scaled by scale*log2e -> exp2-domain softmax.
// Qt/Kt: bf16 [bh][n][d]; Vt: bf16 [b][c][n] (== [bh][d][n]); at: bf16 [b][n][c].
// ---------------------------------------------------------------------------
__global__ __launch_bounds__(256) void attn_kernel(const unsigned short* __restrict__ Qt,
                                                   const unsigned short* __restrict__ Kt,
                                                   const unsigned short* __restrict__ Vt,
                                                   unsigned short* __restrict__ at) {
    __shared__ char smem[32768];
    unsigned short* Qs = (unsigned short*)smem;            // 64 x 128B (swz)
    char* Ks = smem + 8192;
    char* Vs = smem + 16384;
    char* Ps = smem + 24576;

    int q0 = blockIdx.x * 64;
    int bh = blockIdx.y;
    int b = bh >> 3, hh = bh & 7;
    int tid = threadIdx.x;
    int L = tid & 63, w = tid >> 6;
    int g = L >> 4, c = L & 15;

    const unsigned short* Qh = Qt + (size_t)bh * N_DIM * HDIM;
    const unsigned short* Kh = Kt + (size_t)bh * N_DIM * HDIM;
    const unsigned short* Vh = Vt + (size_t)bh * HDIM * N_DIM;

    #pragma unroll
    for (int it = 0; it < 2; ++it) {
        int idx = tid + it * 256;
        int row = idx >> 3, sl = idx & 7;
        bf16x8 v = *(const bf16x8*)&Qh[(size_t)(q0 + row) * HDIM + sl * 8];
        *(bf16x8*)((char*)Qs + row * 128 + ((sl * 16) ^ ((row & 7) << 4))) = v;
    }
    __syncthreads();

    bf16x8 qf[2];
    {
        int row = w * 16 + c;
        #pragma unroll
        for (int ks = 0; ks < 2; ++ks)
            qf[ks] = *(const bf16x8*)((char*)Qs + row * 128 +
                                      ((g * 16 + ks * 64) ^ ((row & 7) << 4)));
    }

    // per-lane staging geometry (rows rowi[i] for K[kpos][d] and V[d][n])
    int rowi[2], ldsoff[2];
    rowi[0] = w * 16 + (L >> 3);
    rowi[1] = rowi[0] + 8;
    #pragma unroll
    for (int i = 0; i < 2; ++i)
        ldsoff[i] = rowi[i] * 128 + (((L & 7) * 16) ^ ((rowi[i] & 7) << 4));

    bf16x8 kreg[2][2], vreg[2][2];
    #pragma unroll
    for (int i = 0; i < 2; ++i) {    // prologue: tile 0 loads
        kreg[0][i] = *(const bf16x8*)&Kh[(size_t)rowi[i] * HDIM + (L & 7) * 8];
        vreg[0][i] = *(const bf16x8*)&Vh[(size_t)rowi[i] * N_DIM + (L & 7) * 8];
    }

    f32x4 oacc[4];
    #pragma unroll
    for (int t = 0; t < 4; ++t) oacc[t] = f32x4{0.f, 0.f, 0.f, 0.f};
    float m_r[4], l_r[4];
    #pragma unroll
    for (int r = 0; r < 4; ++r) { m_r[r] = -INFINITY; l_r[r] = 0.f; }

    for (int kt2 = 0; kt2 < N_DIM / 128; ++kt2) {
        attn_iter<0>(kt2 * 2, L, w, g, c, Kh, Vh, rowi, ldsoff, Ks, Vs, Ps,
                     qf, kreg, vreg, oacc, m_r, l_r);
        attn_iter<1>(kt2 * 2 + 1, L, w, g, c, Kh, Vh, rowi, ldsoff, Ks, Vs, Ps,
                     qf, kreg, vreg, oacc, m_r, l_r);
    }

    // epilogue: O [q][d] bf16 swizzled in LDS, then [b][n][c] global
    float linv[4];
    #pragma unroll
    for (int r = 0; r < 4; ++r) linv[r] = 1.f / l_r[r];
    __syncthreads();
    #pragma unroll
    for (int t = 0; t < 4; ++t)
        #pragma unroll
        for (int r = 0; r < 4; ++r) {
            int d = t * 16 + c;
            int qn = w * 16 + g * 4 + r;
            *(unsigned short*)(smem + qn * 128 + ((d * 2) ^ ((qn & 7) << 4))) =
                f2bf(oacc[t][r] * linv[r]);
        }
    __syncthreads();
    #pragma unroll
    for (int i = 0; i < 2; ++i) {
        int idx = tid + i * 256;       // 512 chunks = 64 rows x 8x16B
        int row = idx >> 3, ch = idx & 7;
        bf16x8 v = *(const bf16x8*)(smem + row * 128 + ((ch * 16) ^ ((row & 7) << 4)));
        *(bf16x8*)&at[((size_t)(b * N_DIM + q0 + row)) * C_DIM + hh * HDIM + ch * 8] = v;
    }
}

// ---------------------------------------------------------------------------
extern "C" void kernel_launch(void* const* d_in, const int* in_sizes, int n_in,
                              void* d_out, int out_size, void* d_ws, size_t ws_size,
                              hipStream_t stream) {
    (void)in_sizes; (void)n_in; (void)out_size; (void)ws_size;
    const float* x     = (const float*)d_in[0];
    const float* gam   = (const float*)d_in[1];
    const float* bet   = (const float*)d_in[2];
    const float* q_w   = (const float*)d_in[3];
    const float* q_b   = (const float*)d_in[4];
    const float* k_w   = (const float*)d_in[5];
    const float* k_b   = (const float*)d_in[6];
    const float* v_w   = (const float*)d_in[7];
    const float* v_b   = (const float*)d_in[8];
    const float* p_w   = (const float*)d_in[9];
    const float* p_b   = (const float*)d_in[10];
    float* out = (float*)d_out;

    const size_t MB = 1 << 20;
    char* wsb = (char*)d_ws;
    unsigned short* ht  = (unsigned short*)(wsb);              // 8 MB  [8192][512]
    unsigned short* wqb = (unsigned short*)(wsb + 8 * MB);     // 512KB each
    unsigned short* wkb = (unsigned short*)(wsb + 8 * MB + 512 * 1024);
    unsigned short* wvb = (unsigned short*)(wsb + 9 * MB);
    unsigned short* wpb = (unsigned short*)(wsb + 9 * MB + 512 * 1024);
    float*          stats = (float*)(wsb + 10 * MB);           // 1 KB
    unsigned short* qt  = (unsigned short*)(wsb + 11 * MB);    // 8 MB [bh][n][d]
    unsigned short* kt  = (unsigned short*)(wsb + 19 * MB);    // 8 MB
    unsigned short* vt  = (unsigned short*)(wsb + 27 * MB);    // 8 MB [b][c][n]
    unsigned short* at  = (unsigned short*)(wsb + 35 * MB);    // 8 MB [b][n][c]

    gn_stats<<<B_DIM * NGRP, 256, 0, stream>>>(x, stats);
    gn_apply_t<<<dim3(N_DIM / 64, C_DIM / 64, B_DIM), 256, 0, stream>>>(x, stats, gam, bet, ht);

    cast_bf16<<<128, 256, 0, stream>>>(q_w, wqb);
    cast_bf16<<<128, 256, 0, stream>>>(k_w, wkb);
    cast_bf16<<<128, 256, 0, stream>>>(v_w, wvb);
    cast_bf16<<<128, 256, 0, stream>>>(p_w, wpb);

    const float escale = 0.044194173824159216f * 1.4426950408889634f;  // scale*log2(e)
    dim3 cgrid(B_DIM * N_DIM / 128, C_DIM / 64);
    conv_mfma<1><<<cgrid, 256, 0, stream>>>(wqb, q_b, ht, nullptr, qt, escale);
    conv_mfma<1><<<cgrid, 256, 0, stream>>>(wkb, k_b, ht, nullptr, kt, 1.0f);
    conv_mfma<0><<<cgrid, 256, 0, stream>>>(wvb, v_b, ht, nullptr, vt, 1.0f);

    attn_kernel<<<dim3(N_DIM / 64, B_DIM * NHEAD), 256, 0, stream>>>(qt, kt, vt, at);

    conv_mfma<2><<<cgrid, 256, 0, stream>>>(wpb, p_b, at, x, out, 1.0f);
}

// Round 6
// 144.451 us; speedup vs baseline: 6.2974x; 1.2237x over previous
//
#include <hip/hip_runtime.h>
#include <hip/hip_bf16.h>
#include <math.h>

#define C_DIM 512
#define N_DIM 2048
#define B_DIM 4
#define NGRP 32
#define GCH 16          // channels per group
#define NHEAD 8
#define HDIM 64
#define EPSV 1e-6f

using f32x4  = __attribute__((ext_vector_type(4))) float;
using bf16x8 = __attribute__((ext_vector_type(8))) short;   // 8 bf16 raw bits (4 VGPRs)

// async global->LDS, 16B per lane; LDS dest = wave-uniform base + lane*16
#define GLL16(gp, lp) __builtin_amdgcn_global_load_lds( \
    (const __attribute__((address_space(1))) unsigned int*)(gp), \
    (__attribute__((address_space(3))) unsigned int*)(lp), 16, 0, 0)

static __device__ __forceinline__ unsigned short f2bf(float f) {
    union { __hip_bfloat16 h; unsigned short u; } cv;
    cv.h = __float2bfloat16(f);
    return cv.u;
}

// ---------------------------------------------------------------------------
// gn_stats: one block per (b,group); group slab contiguous (bg*32768 floats).
// ---------------------------------------------------------------------------
__global__ __launch_bounds__(256) void gn_stats(const float* __restrict__ x,
                                                float* __restrict__ stats) {
    const int GSZ = GCH * N_DIM;            // 32768
    int bg = blockIdx.x;
    const float4* x4 = (const float4*)(x + (size_t)bg * GSZ);
    int tid = threadIdx.x;

    float s = 0.f, ss = 0.f;
    #pragma unroll
    for (int it = 0; it < GSZ / 4 / 256; ++it) {
        float4 v = x4[tid + it * 256];
        s  += v.x + v.y + v.z + v.w;
        ss += v.x * v.x + v.y * v.y + v.z * v.z + v.w * v.w;
    }
    __shared__ float rs[256], rss[256];
    rs[tid] = s; rss[tid] = ss;
    __syncthreads();
    for (int off = 128; off > 0; off >>= 1) {
        if (tid < off) { rs[tid] += rs[tid + off]; rss[tid] += rss[tid + off]; }
        __syncthreads();
    }
    if (tid == 0) {
        float mean = rs[0] * (1.f / GSZ);
        float var  = rss[0] * (1.f / GSZ) - mean * mean;
        stats[bg * 2]     = mean;
        stats[bg * 2 + 1] = rsqrtf(var + EPSV);
    }
}

// ---------------------------------------------------------------------------
// gn_apply_t: x [b][c][n] fp32 -> ht [(b*n)][c] bf16 (normalized, transposed).
// ---------------------------------------------------------------------------
__global__ __launch_bounds__(256) void gn_apply_t(const float* __restrict__ x,
                                                  const float* __restrict__ stats,
                                                  const float* __restrict__ gamma,
                                                  const float* __restrict__ beta,
                                                  unsigned short* __restrict__ ht) {
    __shared__ char smem[8192];     // [64 n][64 c] bf16, rows 128B, XOR-swizzled
    int n0 = blockIdx.x * 64, c0 = blockIdx.y * 64, b = blockIdx.z;
    int tid = threadIdx.x;
    #pragma unroll
    for (int it = 0; it < 4; ++it) {
        int idx = tid + it * 256;
        int ci = idx >> 4, n4 = (idx & 15) << 2;
        int cg = c0 + ci, grp = cg >> 4;
        float mean = stats[(b * NGRP + grp) * 2];
        float rstd = stats[(b * NGRP + grp) * 2 + 1];
        float ga = gamma[cg] * rstd, be = beta[cg] - mean * ga;
        float4 v = *(const float4*)&x[((size_t)b * C_DIM + cg) * N_DIM + n0 + n4];
        float vals[4] = {v.x, v.y, v.z, v.w};
        #pragma unroll
        for (int j = 0; j < 4; ++j) {
            int nl = n4 + j;
            *(unsigned short*)(smem + nl * 128 + ((ci * 2) ^ ((nl & 7) << 4))) =
                f2bf(vals[j] * ga + be);
        }
    }
    __syncthreads();
    #pragma unroll
    for (int i = 0; i < 2; ++i) {
        int idx = tid + i * 256;       // 512 chunks = 64 rows x 8x16B
        int row = idx >> 3, ch = idx & 7;
        bf16x8 v = *(const bf16x8*)(smem + row * 128 + ((ch * 16) ^ ((row & 7) << 4)));
        *(bf16x8*)&ht[((size_t)(b * N_DIM + n0 + row)) * C_DIM + c0 + ch * 8] = v;
    }
}

// ---------------------------------------------------------------------------
// cast_bf16: fp32 -> bf16 raw, 8 elems/thread
// ---------------------------------------------------------------------------
__global__ __launch_bounds__(256) void cast_bf16(const float* __restrict__ src,
                                                 unsigned short* __restrict__ dst) {
    size_t idx = (size_t)blockIdx.x * 256 + threadIdx.x;
    const float4* s4 = (const float4*)src;
    float4 a = s4[idx * 2], b = s4[idx * 2 + 1];
    bf16x8 o;
    o[0] = (short)f2bf(a.x); o[1] = (short)f2bf(a.y);
    o[2] = (short)f2bf(a.z); o[3] = (short)f2bf(a.w);
    o[4] = (short)f2bf(b.x); o[5] = (short)f2bf(b.y);
    o[6] = (short)f2bf(b.z); o[7] = (short)f2bf(b.w);
    *(bf16x8*)&dst[idx * 8] = o;
}

// ---------------------------------------------------------------------------
// conv_mfma: D[o][bn] = sum_c W[o][c] * ht[bn][c]  (+bias, modes below)
// Tile BM=64(o) x BN=128(bn) x BK=64. 4 waves, each 32x64.
// MODE 0: out bf16 natural [b][c][n]         (V conv)
// MODE 1: out bf16 [bh][n][d], *escale       (Q/K convs; one head per block)
// MODE 2: out fp32 [b][c][n] + res           (proj conv)
// ---------------------------------------------------------------------------
template <int MODE>
__global__ __launch_bounds__(256) void conv_mfma(const unsigned short* __restrict__ Wb,
                                                 const float* __restrict__ bias,
                                                 const unsigned short* __restrict__ Bsrc,
                                                 const float* __restrict__ res,
                                                 void* __restrict__ outp,
                                                 float escale) {
    __shared__ char smem[24576];
    unsigned short* As = (unsigned short*)smem;           // [64 o][64 k] swz, 8KB
    unsigned short* Bs = (unsigned short*)(smem + 8192);  // [128 n][64 k] swz, 16KB

    int bn0 = blockIdx.x * 128;      // flattened b*N + n
    int bo  = blockIdx.y * 64;
    int tid = threadIdx.x;
    int L = tid & 63, w = tid >> 6;
    int g = L >> 4, c = L & 15;
    int wr = w >> 1, wc = w & 1;

    f32x4 acc[2][4];
    #pragma unroll
    for (int t = 0; t < 2; ++t)
        #pragma unroll
        for (int u = 0; u < 4; ++u) acc[t][u] = f32x4{0.f, 0.f, 0.f, 0.f};

    for (int k0 = 0; k0 < C_DIM; k0 += 64) {
        #pragma unroll
        for (int i = 0; i < 2; ++i) {
            int j = w * 2 + i;
            int ra = j * 8 + (L >> 3);
            int sl = (L & 7) ^ (ra & 7);
            GLL16(Wb + (size_t)(bo + ra) * C_DIM + k0 + sl * 8, (char*)As + j * 1024);
        }
        #pragma unroll
        for (int i = 0; i < 4; ++i) {
            int j = w * 4 + i;
            int rb = j * 8 + (L >> 3);
            int sl = (L & 7) ^ (rb & 7);
            GLL16(Bsrc + (size_t)(bn0 + rb) * C_DIM + k0 + sl * 8, (char*)Bs + j * 1024);
        }
        __syncthreads();

        bf16x8 af[2][2], bfr[4][2];
        #pragma unroll
        for (int t = 0; t < 2; ++t) {
            int row = wr * 32 + t * 16 + c;
            #pragma unroll
            for (int ks = 0; ks < 2; ++ks)
                af[t][ks] = *(const bf16x8*)((char*)As + row * 128 +
                                             ((g * 16 + ks * 64) ^ ((row & 7) << 4)));
        }
        #pragma unroll
        for (int u = 0; u < 4; ++u) {
            int row = wc * 64 + u * 16 + c;
            #pragma unroll
            for (int ks = 0; ks < 2; ++ks)
                bfr[u][ks] = *(const bf16x8*)((char*)Bs + row * 128 +
                                              ((g * 16 + ks * 64) ^ ((row & 7) << 4)));
        }
        #pragma unroll
        for (int ks = 0; ks < 2; ++ks)
            #pragma unroll
            for (int t = 0; t < 2; ++t)
                #pragma unroll
                for (int u = 0; u < 4; ++u)
                    acc[t][u] = __builtin_amdgcn_mfma_f32_16x16x32_bf16(
                        af[t][ks], bfr[u][ks], acc[t][u], 0, 0, 0);
        __syncthreads();
    }

    int b  = bn0 >> 11;              // N_DIM = 2048
    int nb = bn0 & (N_DIM - 1);

    if (MODE == 0) {
        unsigned short* vt = (unsigned short*)outp;
        #pragma unroll
        for (int t = 0; t < 2; ++t)
            #pragma unroll
            for (int r = 0; r < 4; ++r) {
                int m = bo + wr * 32 + t * 16 + g * 4 + r;
                float bi = bias[m];
                #pragma unroll
                for (int u = 0; u < 4; ++u) {
                    int n = nb + wc * 64 + u * 16 + c;
                    vt[((size_t)b * C_DIM + m) * N_DIM + n] = f2bf(acc[t][u][r] + bi);
                }
            }
    } else if (MODE == 1) {
        int hh = bo >> 6;            // BM=64 => one head per block
        int bh = b * NHEAD + hh;
        unsigned short* Ts = (unsigned short*)smem;   // [128 n][64 d] swz, 16KB
        __syncthreads();
        #pragma unroll
        for (int t = 0; t < 2; ++t)
            #pragma unroll
            for (int r = 0; r < 4; ++r) {
                int ml = wr * 32 + t * 16 + g * 4 + r;   // d
                float bi = bias[bo + ml];
                #pragma unroll
                for (int u = 0; u < 4; ++u) {
                    int nl = wc * 64 + u * 16 + c;
                    *(unsigned short*)((char*)Ts + nl * 128 + ((ml * 2) ^ ((nl & 7) << 4))) =
                        f2bf((acc[t][u][r] + bi) * escale);
                }
            }
        __syncthreads();
        unsigned short* qt = (unsigned short*)outp;
        #pragma unroll
        for (int i = 0; i < 4; ++i) {
            int idx = tid + i * 256;     // 1024 chunks = 128 rows x 8x16B
            int row = idx >> 3, ch = idx & 7;
            bf16x8 v = *(const bf16x8*)((char*)Ts + row * 128 + ((ch * 16) ^ ((row & 7) << 4)));
            *(bf16x8*)&qt[((size_t)bh * N_DIM + nb + row) * HDIM + ch * 8] = v;
        }
    } else {
        float* outf = (float*)outp;
        #pragma unroll
        for (int t = 0; t < 2; ++t)
            #pragma unroll
            for (int r = 0; r < 4; ++r) {
                int m = bo + wr * 32 + t * 16 + g * 4 + r;
                float bi = bias[m];
                #pragma unroll
                for (int u = 0; u < 4; ++u) {
                    int n = nb + wc * 64 + u * 16 + c;
                    size_t off = ((size_t)b * C_DIM + m) * N_DIM + n;
                    outf[off] = acc[t][u][r] + bi + res[off];
                }
            }
    }
}

// ---------------------------------------------------------------------------
// attn iteration. SWAPPED operands: S^T = mfma(K,Q) so each lane owns one
// q-row (q = 16w+c) with kpos lane-local -> softmax reduce = in-lane + 2 shfl.
// P packed to bf16 in-register, wave-private P^T[q][kpos] strip in LDS.
// ---------------------------------------------------------------------------
template <int CUR>
__device__ __forceinline__ void attn_iter(
    int kt, int L, int w, int g, int c,
    const unsigned short* __restrict__ Kh, const unsigned short* __restrict__ Vh,
    const int rowi[2], const int ldsoff[2],
    char* Ks, char* Vs, char* Ps,
    const bf16x8 qf[2], bf16x8 (&kreg)[2][2], bf16x8 (&vreg)[2][2],
    f32x4 (&oacc)[4], float& m_r, float& l_r)
{
    const int NXT = CUR ^ 1;
    __syncthreads();                 // prev iter's Ks/Vs reads done
    #pragma unroll
    for (int i = 0; i < 2; ++i) {
        *(bf16x8*)(Ks + ldsoff[i]) = kreg[CUR][i];
        *(bf16x8*)(Vs + ldsoff[i]) = vreg[CUR][i];
    }
    if (kt < N_DIM / 64 - 1) {       // issue next tile's loads (T14)
        int k0n = (kt + 1) * 64;
        #pragma unroll
        for (int i = 0; i < 2; ++i) {
            kreg[NXT][i] = *(const bf16x8*)&Kh[(size_t)(k0n + rowi[i]) * HDIM + (L & 7) * 8];
            vreg[NXT][i] = *(const bf16x8*)&Vh[(size_t)rowi[i] * N_DIM + k0n + (L & 7) * 8];
        }
    }
    __syncthreads();                 // Ks/Vs visible to all waves

    // ---- S^T = K Q^T : D[kpos=16t+4g+r][q=16w+c] ----
    f32x4 sacc[4];
    #pragma unroll
    for (int t = 0; t < 4; ++t) sacc[t] = f32x4{0.f, 0.f, 0.f, 0.f};
    __builtin_amdgcn_s_setprio(1);
    #pragma unroll
    for (int t = 0; t < 4; ++t) {
        int row = t * 16 + c;
        #pragma unroll
        for (int ks = 0; ks < 2; ++ks) {
            bf16x8 kf = *(const bf16x8*)(Ks + row * 128 +
                                         ((g * 16 + ks * 64) ^ ((row & 7) << 4)));
            sacc[t] = __builtin_amdgcn_mfma_f32_16x16x32_bf16(kf, qf[ks], sacc[t], 0, 0, 0);
        }
    }
    __builtin_amdgcn_s_setprio(0);

    // ---- softmax over kpos (exp2 domain): in-lane 16 + 2 shfl ----
    float mloc = fmaxf(
        fmaxf(fmaxf(fmaxf(sacc[0][0], sacc[0][1]), fmaxf(sacc[0][2], sacc[0][3])),
              fmaxf(fmaxf(sacc[1][0], sacc[1][1]), fmaxf(sacc[1][2], sacc[1][3]))),
        fmaxf(fmaxf(fmaxf(sacc[2][0], sacc[2][1]), fmaxf(sacc[2][2], sacc[2][3])),
              fmaxf(fmaxf(sacc[3][0], sacc[3][1]), fmaxf(sacc[3][2], sacc[3][3]))));
    mloc = fmaxf(mloc, __shfl_xor(mloc, 16));
    mloc = fmaxf(mloc, __shfl_xor(mloc, 32));
    if (!__all(mloc - m_r <= 6.0f)) {     // T13 defer-max
        float mn = fmaxf(m_r, mloc);
        float fac = exp2f(m_r - mn);
        m_r = mn;
        l_r *= fac;
        #pragma unroll
        for (int t = 0; t < 4; ++t) oacc[t] = oacc[t] * fac;
    }
    float rs = 0.f;
    unsigned pk[4][2];
    #pragma unroll
    for (int t = 0; t < 4; ++t) {
        float p0 = exp2f(sacc[t][0] - m_r);
        float p1 = exp2f(sacc[t][1] - m_r);
        float p2 = exp2f(sacc[t][2] - m_r);
        float p3 = exp2f(sacc[t][3] - m_r);
        rs += (p0 + p1) + (p2 + p3);
        pk[t][0] = (unsigned)f2bf(p0) | ((unsigned)f2bf(p1) << 16);
        pk[t][1] = (unsigned)f2bf(p2) | ((unsigned)f2bf(p3) << 16);
    }
    rs += __shfl_xor(rs, 16);
    rs += __shfl_xor(rs, 32);
    l_r += rs;

    // ---- P^T strip rows 16w..16w+15 (wave-private) [q][kpos] swizzled ----
    int prow = w * 16 + c;
    int psw = (prow & 7) << 4;
    char* pb = Ps + prow * 128;
    #pragma unroll
    for (int t = 0; t < 4; ++t)
        *(unsigned long long*)(pb + ((t * 32 + g * 8) ^ psw)) =
            (unsigned long long)pk[t][0] | ((unsigned long long)pk[t][1] << 32);

    // ---- O^T += V^T P^T : D[d=16t+4g+r][q=16w+c] ----
    __builtin_amdgcn_s_setprio(1);
    #pragma unroll
    for (int ks = 0; ks < 2; ++ks) {
        bf16x8 pf = *(const bf16x8*)(pb + ((ks * 64 + g * 16) ^ psw));
        #pragma unroll
        for (int t = 0; t < 4; ++t) {
            int vrow = t * 16 + c;
            bf16x8 vf = *(const bf16x8*)(Vs + vrow * 128 +
                                         ((g * 16 + ks * 64) ^ ((vrow & 7) << 4)));
            oacc[t] = __builtin_amdgcn_mfma_f32_16x16x32_bf16(vf, pf, oacc[t], 0, 0, 0);
        }
    }
    __builtin_amdgcn_s_setprio(0);
}

// ---------------------------------------------------------------------------
// MFMA bf16 flash attention (swapped-operand form).
// Qt/Kt: bf16 [bh][n][d]; Vt: bf16 [b][c][n] (== [bh][d][n]); at: bf16 [b][n][c].
// ---------------------------------------------------------------------------
__global__ __launch_bounds__(256) void attn_kernel(const unsigned short* __restrict__ Qt,
                                                   const unsigned short* __restrict__ Kt,
                                                   const unsigned short* __restrict__ Vt,
                                                   unsigned short* __restrict__ at) {
    __shared__ char smem[32768];
    unsigned short* Qs = (unsigned short*)smem;            // 64 x 128B (swz)
    char* Ks = smem + 8192;
    char* Vs = smem + 16384;
    char* Ps = smem + 24576;

    int q0 = blockIdx.x * 64;
    int bh = blockIdx.y;
    int b = bh >> 3, hh = bh & 7;
    int tid = threadIdx.x;
    int L = tid & 63, w = tid >> 6;
    int g = L >> 4, c = L & 15;

    const unsigned short* Qh = Qt + (size_t)bh * N_DIM * HDIM;
    const unsigned short* Kh = Kt + (size_t)bh * N_DIM * HDIM;
    const unsigned short* Vh = Vt + (size_t)bh * HDIM * N_DIM;

    #pragma unroll
    for (int it = 0; it < 2; ++it) {
        int idx = tid + it * 256;
        int row = idx >> 3, sl = idx & 7;
        bf16x8 v = *(const bf16x8*)&Qh[(size_t)(q0 + row) * HDIM + sl * 8];
        *(bf16x8*)((char*)Qs + row * 128 + ((sl * 16) ^ ((row & 7) << 4))) = v;
    }
    __syncthreads();

    bf16x8 qf[2];                    // B-operand: col=c -> q=16w+c, k=d
    {
        int row = w * 16 + c;
        #pragma unroll
        for (int ks = 0; ks < 2; ++ks)
            qf[ks] = *(const bf16x8*)((char*)Qs + row * 128 +
                                      ((g * 16 + ks * 64) ^ ((row & 7) << 4)));
    }

    // per-lane staging geometry (rows rowi[i] for K[kpos][d] and V[d][n])
    int rowi[2], ldsoff[2];
    rowi[0] = w * 16 + (L >> 3);
    rowi[1] = rowi[0] + 8;
    #pragma unroll
    for (int i = 0; i < 2; ++i)
        ldsoff[i] = rowi[i] * 128 + (((L & 7) * 16) ^ ((rowi[i] & 7) << 4));

    bf16x8 kreg[2][2], vreg[2][2];
    #pragma unroll
    for (int i = 0; i < 2; ++i) {    // prologue: tile 0 loads
        kreg[0][i] = *(const bf16x8*)&Kh[(size_t)rowi[i] * HDIM + (L & 7) * 8];
        vreg[0][i] = *(const bf16x8*)&Vh[(size_t)rowi[i] * N_DIM + (L & 7) * 8];
    }

    f32x4 oacc[4];
    #pragma unroll
    for (int t = 0; t < 4; ++t) oacc[t] = f32x4{0.f, 0.f, 0.f, 0.f};
    float m_r = -INFINITY, l_r = 0.f;

    for (int kt2 = 0; kt2 < N_DIM / 128; ++kt2) {
        attn_iter<0>(kt2 * 2, L, w, g, c, Kh, Vh, rowi, ldsoff, Ks, Vs, Ps,
                     qf, kreg, vreg, oacc, m_r, l_r);
        attn_iter<1>(kt2 * 2 + 1, L, w, g, c, Kh, Vh, rowi, ldsoff, Ks, Vs, Ps,
                     qf, kreg, vreg, oacc, m_r, l_r);
    }

    // epilogue: lane holds O^T[d=16t+4g+r][q=16w+c], single l.
    float oinv = 1.f / l_r;
    __syncthreads();
    {
        int orow = w * 16 + c;           // q-local row
        int osw = (orow & 7) << 4;
        char* ob = smem + orow * 128;
        #pragma unroll
        for (int t = 0; t < 4; ++t) {
            unsigned lo = (unsigned)f2bf(oacc[t][0] * oinv) |
                          ((unsigned)f2bf(oacc[t][1] * oinv) << 16);
            unsigned hi = (unsigned)f2bf(oacc[t][2] * oinv) |
                          ((unsigned)f2bf(oacc[t][3] * oinv) << 16);
            *(unsigned long long*)(ob + ((t * 32 + g * 8) ^ osw)) =
                (unsigned long long)lo | ((unsigned long long)hi << 32);
        }
    }
    __syncthreads();
    #pragma unroll
    for (int i = 0; i < 2; ++i) {
        int idx = tid + i * 256;       // 512 chunks = 64 rows x 8x16B
        int row = idx >> 3, ch = idx & 7;
        bf16x8 v = *(const bf16x8*)(smem + row * 128 + ((ch * 16) ^ ((row & 7) << 4)));
        *(bf16x8*)&at[((size_t)(b * N_DIM + q0 + row)) * C_DIM + hh * HDIM + ch * 8] = v;
    }
}

// ---------------------------------------------------------------------------
extern "C" void kernel_launch(void* const* d_in, const int* in_sizes, int n_in,
                              void* d_out, int out_size, void* d_ws, size_t ws_size,
                              hipStream_t stream) {
    (void)in_sizes; (void)n_in; (void)out_size; (void)ws_size;
    const float* x     = (const float*)d_in[0];
    const float* gam   = (const float*)d_in[1];
    const float* bet   = (const float*)d_in[2];
    const float* q_w   = (const float*)d_in[3];
    const float* q_b   = (const float*)d_in[4];
    const float* k_w   = (const float*)d_in[5];
    const float* k_b   = (const float*)d_in[6];
    const float* v_w   = (const float*)d_in[7];
    const float* v_b   = (const float*)d_in[8];
    const float* p_w   = (const float*)d_in[9];
    const float* p_b   = (const float*)d_in[10];
    float* out = (float*)d_out;

    const size_t MB = 1 << 20;
    char* wsb = (char*)d_ws;
    unsigned short* ht  = (unsigned short*)(wsb);              // 8 MB  [8192][512]
    unsigned short* wqb = (unsigned short*)(wsb + 8 * MB);     // 512KB each
    unsigned short* wkb = (unsigned short*)(wsb + 8 * MB + 512 * 1024);
    unsigned short* wvb = (unsigned short*)(wsb + 9 * MB);
    unsigned short* wpb = (unsigned short*)(wsb + 9 * MB + 512 * 1024);
    float*          stats = (float*)(wsb + 10 * MB);           // 1 KB
    unsigned short* qt  = (unsigned short*)(wsb + 11 * MB);    // 8 MB [bh][n][d]
    unsigned short* kt  = (unsigned short*)(wsb + 19 * MB);    // 8 MB
    unsigned short* vt  = (unsigned short*)(wsb + 27 * MB);    // 8 MB [b][c][n]
    unsigned short* at  = (unsigned short*)(wsb + 35 * MB);    // 8 MB [b][n][c]

    gn_stats<<<B_DIM * NGRP, 256, 0, stream>>>(x, stats);
    gn_apply_t<<<dim3(N_DIM / 64, C_DIM / 64, B_DIM), 256, 0, stream>>>(x, stats, gam, bet, ht);

    cast_bf16<<<128, 256, 0, stream>>>(q_w, wqb);
    cast_bf16<<<128, 256, 0, stream>>>(k_w, wkb);
    cast_bf16<<<128, 256, 0, stream>>>(v_w, wvb);
    cast_bf16<<<128, 256, 0, stream>>>(p_w, wpb);

    const float escale = 0.044194173824159216f * 1.4426950408889634f;  // scale*log2(e)
    dim3 cgrid(B_DIM * N_DIM / 128, C_DIM / 64);
    conv_mfma<1><<<cgrid, 256, 0, stream>>>(wqb, q_b, ht, nullptr, qt, escale);
    conv_mfma<1><<<cgrid, 256, 0, stream>>>(wkb, k_b, ht, nullptr, kt, 1.0f);
    conv_mfma<0><<<cgrid, 256, 0, stream>>>(wvb, v_b, ht, nullptr, vt, 1.0f);

    attn_kernel<<<dim3(N_DIM / 64, B_DIM * NHEAD), 256, 0, stream>>>(qt, kt, vt, at);

    conv_mfma<2><<<cgrid, 256, 0, stream>>>(wpb, p_b, at, x, out, 1.0f);
}